// Round 3
// baseline (2106.195 us; speedup 1.0000x reference)
//
#include <hip/hip_runtime.h>

#define NFEAT 64
#define NCAT 192
#define BN_NODES 32
#define BN_SPAN 8

__device__ __forceinline__ float bf2f(unsigned int u16) {
    union { unsigned int i; float f; } c; c.i = u16 << 16; return c.f;
}
__device__ __forceinline__ unsigned short f2bf(float f) {
    union { float f; unsigned int i; } c; c.f = f;
    unsigned int r = c.i + 0x7fffu + ((c.i >> 16) & 1u);
    return (unsigned short)(r >> 16);
}

__global__ void deg_kernel(const int* __restrict__ dst, int* __restrict__ deg, int nedges) {
    int e = blockIdx.x * blockDim.x + threadIdx.x;
    if (e < nedges) atomicAdd(&deg[dst[e]], 1);
}

__global__ void cnt_kernel(const int* __restrict__ batch, float* __restrict__ cnt, int n) {
    int i = blockIdx.x * blockDim.x + threadIdx.x;
    if (i < n) atomicAdd(&cnt[batch[i]], 1.0f);
}

__global__ void recip_kernel(const int* __restrict__ deg, float* __restrict__ recip, int n) {
    int i = blockIdx.x * blockDim.x + threadIdx.x;
    if (i < n) recip[i] = 1.0f / (float)max(deg[i], 1);
}

__global__ void cvt_kernel(const float* __restrict__ x, unsigned short* __restrict__ xb, int total4) {
    int t = blockIdx.x * blockDim.x + threadIdx.x;
    if (t < total4) {
        float4 v = reinterpret_cast<const float4*>(x)[t];
        ushort4 o;
        o.x = f2bf(v.x); o.y = f2bf(v.y); o.z = f2bf(v.z); o.w = f2bf(v.w);
        reinterpret_cast<ushort4*>(xb)[t] = o;
    }
}

// Single-block exclusive scan over deg -> row_start (and cursor copy).
__global__ __launch_bounds__(1024) void scan_kernel(const int* __restrict__ deg,
                                                    int* __restrict__ row_start,
                                                    int* __restrict__ cursor, int n) {
    __shared__ int wtot[16];
    __shared__ int woff[16];
    __shared__ int carry_s;
    int tid = threadIdx.x, lane = tid & 63, wid = tid >> 6;
    if (tid == 0) carry_s = 0;
    __syncthreads();
    for (int base = 0; base < n; base += 1024) {
        int i = base + tid;
        int v = (i < n) ? deg[i] : 0;
        int incl = v;
#pragma unroll
        for (int off = 1; off < 64; off <<= 1) {
            int t = __shfl_up(incl, off);
            if (lane >= off) incl += t;
        }
        if (lane == 63) wtot[wid] = incl;
        __syncthreads();
        if (wid == 0) {
            int wv = (lane < 16) ? wtot[lane] : 0;
            int winc = wv;
#pragma unroll
            for (int off = 1; off < 16; off <<= 1) {
                int t = __shfl_up(winc, off);
                if (lane >= off) winc += t;
            }
            if (lane < 16) woff[lane] = winc - wv;
        }
        __syncthreads();
        int carry = carry_s;
        int excl = carry + woff[wid] + (incl - v);
        if (i < n) { row_start[i] = excl; cursor[i] = excl; }
        int ctot = woff[15] + wtot[15];
        __syncthreads();
        if (tid == 0) carry_s = carry + ctot;
        __syncthreads();
    }
}

__global__ void fill_kernel(const int* __restrict__ src, const int* __restrict__ dst,
                            int* __restrict__ cursor, int* __restrict__ csr_src, int ne) {
    int e = blockIdx.x * blockDim.x + threadIdx.x;
    if (e < ne) {
        int d = dst[e];
        int pos = atomicAdd(&cursor[d], 1);
        csr_src[pos] = src[e];
    }
}

// Wave-per-node CSR mean-gather from bf16 features. 8 neighbors in flight:
// lane = (slot g = lane>>3, feature-octet q = lane&7), 16B loads, butterfly reduce.
// Folds 1/deg. Writes fp32 agg row. No LDS -> high occupancy for latency hiding.
__global__ __launch_bounds__(256, 8) void gather_kernel(
    const unsigned short* __restrict__ xb, const int* __restrict__ row_start,
    const int* __restrict__ deg, const float* __restrict__ recip,
    const int* __restrict__ csr_src, float* __restrict__ agg, int n) {
    int lane = threadIdx.x & 63;
    int i = (blockIdx.x * blockDim.x + threadIdx.x) >> 6;
    if (i >= n) return;
    int rs = row_start[i], dg = deg[i];
    int g = lane >> 3, q = lane & 7;
    float av[8];
#pragma unroll
    for (int c = 0; c < 8; ++c) av[c] = 0.0f;

    for (int base = 0; base < dg; base += 64) {
        int cnt = min(dg - base, 64);
        int myidx = (lane < cnt) ? csr_src[rs + base + lane] : 0;
        for (int p = 0; p < cnt; p += 8) {
            int slot = p + g;
            int nb = __shfl(myidx, slot);
            if (slot < cnt) {
                const uint4 v = *reinterpret_cast<const uint4*>(xb + (size_t)nb * NFEAT + q * 8);
                av[0] += bf2f(v.x & 0xffffu);
                av[1] += bf2f(v.x >> 16);
                av[2] += bf2f(v.y & 0xffffu);
                av[3] += bf2f(v.y >> 16);
                av[4] += bf2f(v.z & 0xffffu);
                av[5] += bf2f(v.z >> 16);
                av[6] += bf2f(v.w & 0xffffu);
                av[7] += bf2f(v.w >> 16);
            }
        }
    }
#pragma unroll
    for (int c = 0; c < 8; ++c) {
        av[c] += __shfl_xor(av[c], 8);
        av[c] += __shfl_xor(av[c], 16);
        av[c] += __shfl_xor(av[c], 32);
    }
    if (g == 0) {
        float r = recip[i];
        float4* dst4 = reinterpret_cast<float4*>(agg + (size_t)i * NFEAT + q * 8);
        dst4[0] = make_float4(av[0] * r, av[1] * r, av[2] * r, av[3] * r);
        dst4[1] = make_float4(av[4] * r, av[5] * r, av[6] * r, av[7] * r);
    }
}

// Dual matmul h = agg@WlT + bl + x@WrT, 4 nodes per wave per iteration.
// Weights in LDS packed per-lane-contiguous float4 (conflict-free b128);
// node data staged per-wave in LDS, read back as uniform-address b128 broadcasts.
// Accumulates BN sum/sumsq into stats.
__global__ __launch_bounds__(256, 4) void lin_kernel(
    const float* __restrict__ agg, const float* __restrict__ xin,
    const float* __restrict__ Wl, const float* __restrict__ bl,
    const float* __restrict__ Wr,
    float* __restrict__ h, float* __restrict__ stats, int n) {
    __shared__ float4 wlq[16 * 64];
    __shared__ float4 wrq[16 * 64];
    __shared__ float4 avs[4][64];
    __shared__ float4 xvs[4][64];

    for (int t = threadIdx.x; t < 1024; t += 256) {
        int j = t >> 4, q = t & 15;
        wlq[q * 64 + j] = reinterpret_cast<const float4*>(Wl)[t];
        wrq[q * 64 + j] = reinterpret_cast<const float4*>(Wr)[t];
    }
    __syncthreads();

    int lane = threadIdx.x & 63;
    int wave = threadIdx.x >> 6;
    int gwave = blockIdx.x * 4 + wave;
    int nwaves = gridDim.x * 4;
    int m = lane >> 4, q4 = lane & 15;

    float blj = bl[lane];
    float s1 = 0.0f, s2 = 0.0f;
    float4 zero4 = make_float4(0.f, 0.f, 0.f, 0.f);

    for (int i0 = gwave * 4; i0 < n; i0 += nwaves * 4) {
        int i = i0 + m;
        bool valid = (i < n);
        float4 ag = valid ? reinterpret_cast<const float4*>(agg)[(size_t)i * 16 + q4] : zero4;
        float4 xg = valid ? reinterpret_cast<const float4*>(xin)[(size_t)i * 16 + q4] : zero4;
        avs[wave][lane] = ag;
        xvs[wave][lane] = xg;

        float acc0 = blj, acc1 = blj, acc2 = blj, acc3 = blj;
#pragma unroll
        for (int q = 0; q < 16; ++q) {
            float4 wl4 = wlq[q * 64 + lane];
            float4 wr4 = wrq[q * 64 + lane];
            float4 a0 = avs[wave][q];      float4 x0 = xvs[wave][q];
            acc0 += a0.x * wl4.x + a0.y * wl4.y + a0.z * wl4.z + a0.w * wl4.w
                  + x0.x * wr4.x + x0.y * wr4.y + x0.z * wr4.z + x0.w * wr4.w;
            float4 a1 = avs[wave][16 + q]; float4 x1 = xvs[wave][16 + q];
            acc1 += a1.x * wl4.x + a1.y * wl4.y + a1.z * wl4.z + a1.w * wl4.w
                  + x1.x * wr4.x + x1.y * wr4.y + x1.z * wr4.z + x1.w * wr4.w;
            float4 a2 = avs[wave][32 + q]; float4 x2 = xvs[wave][32 + q];
            acc2 += a2.x * wl4.x + a2.y * wl4.y + a2.z * wl4.z + a2.w * wl4.w
                  + x2.x * wr4.x + x2.y * wr4.y + x2.z * wr4.z + x2.w * wr4.w;
            float4 a3 = avs[wave][48 + q]; float4 x3 = xvs[wave][48 + q];
            acc3 += a3.x * wl4.x + a3.y * wl4.y + a3.z * wl4.z + a3.w * wl4.w
                  + x3.x * wr4.x + x3.y * wr4.y + x3.z * wr4.z + x3.w * wr4.w;
        }
        if (i0 + 3 < n) {
            h[(size_t)(i0 + 0) * NFEAT + lane] = acc0;
            h[(size_t)(i0 + 1) * NFEAT + lane] = acc1;
            h[(size_t)(i0 + 2) * NFEAT + lane] = acc2;
            h[(size_t)(i0 + 3) * NFEAT + lane] = acc3;
            s1 += acc0 + acc1 + acc2 + acc3;
            s2 += acc0 * acc0 + acc1 * acc1 + acc2 * acc2 + acc3 * acc3;
        } else {
            if (i0 + 0 < n) { h[(size_t)(i0 + 0) * NFEAT + lane] = acc0; s1 += acc0; s2 += acc0 * acc0; }
            if (i0 + 1 < n) { h[(size_t)(i0 + 1) * NFEAT + lane] = acc1; s1 += acc1; s2 += acc1 * acc1; }
            if (i0 + 2 < n) { h[(size_t)(i0 + 2) * NFEAT + lane] = acc2; s1 += acc2; s2 += acc2 * acc2; }
        }
    }

    __syncthreads();
    float* red1 = reinterpret_cast<float*>(avs);
    float* red2 = reinterpret_cast<float*>(xvs);
    red1[threadIdx.x] = s1;
    red2[threadIdx.x] = s2;
    __syncthreads();
    if (wave == 0) {
        float t1 = red1[lane] + red1[64 + lane] + red1[128 + lane] + red1[192 + lane];
        float t2 = red2[lane] + red2[64 + lane] + red2[128 + lane] + red2[192 + lane];
        atomicAdd(&stats[lane], t1);
        atomicAdd(&stats[64 + lane], t2);
    }
}

// BN (training stats) + ReLU in place; optional bf16 copy for next layer's gather;
// pool accumulation via LDS (batch sorted).
__global__ __launch_bounds__(256) void bn_kernel(
    float* __restrict__ h, unsigned short* __restrict__ hbf,
    const float* __restrict__ stats,
    const float* __restrict__ g, const float* __restrict__ b,
    const int* __restrict__ batch, float* __restrict__ pool,
    int colbase, int n) {
    __shared__ float pl[BN_SPAN][64];
    __shared__ int gmin_s, span_s;
    int tid = threadIdx.x;
    int j = tid & 63;
    int sub = tid >> 6;
    int nbase = blockIdx.x * BN_NODES;
    if (nbase >= n) return;

    if (tid == 0) {
        int last = min(nbase + BN_NODES, n) - 1;
        gmin_s = batch[nbase];
        span_s = batch[last] - gmin_s + 1;
    }
    __syncthreads();
    int gmin = gmin_s, span = span_s;
    bool use_lds = (span <= BN_SPAN);
    if (use_lds) {
        for (int t = tid; t < span * 64; t += 256) ((float*)pl)[t] = 0.0f;
    }
    __syncthreads();

    float invn = 1.0f / (float)n;
    float mu = stats[j] * invn;
    float var = stats[64 + j] * invn - mu * mu;
    float sc = rsqrtf(var + 1e-5f) * g[j];
    float bb = b[j];

    for (int r = sub; r < BN_NODES; r += 4) {
        int i = nbase + r;
        if (i >= n) break;
        size_t idx = (size_t)i * NFEAT + j;
        float v = fmaxf((h[idx] - mu) * sc + bb, 0.0f);
        h[idx] = v;
        if (hbf) hbf[idx] = f2bf(v);
        int gi = batch[i];
        if (use_lds) atomicAdd(&pl[gi - gmin][j], v);
        else atomicAdd(&pool[(size_t)gi * NCAT + colbase + j], v);
    }
    __syncthreads();
    if (use_lds) {
        for (int t = tid; t < span * 64; t += 256) {
            int s = t >> 6, j2 = t & 63;
            float v = pl[s][j2];
            if (v != 0.0f) atomicAdd(&pool[(size_t)(gmin + s) * NCAT + colbase + j2], v);
        }
    }
}

__global__ void final_kernel(const float* __restrict__ pool, const float* __restrict__ cnt,
                             float* __restrict__ out, int total) {
    int t = blockIdx.x * blockDim.x + threadIdx.x;
    if (t >= total) return;
    int gidx = t / NCAT;
    out[t] = pool[t] / fmaxf(cnt[gidx], 1.0f);
}

extern "C" void kernel_launch(void* const* d_in, const int* in_sizes, int n_in,
                              void* d_out, int out_size, void* d_ws, size_t ws_size,
                              hipStream_t stream) {
    const float* x = (const float*)d_in[0];
    const int* ei = (const int*)d_in[1];
    const int* batch = (const int*)d_in[2];

    const float* Wl[3], *bl[3], *Wr[3], *gm[3], *bt[3];
    for (int L = 0; L < 3; ++L) {
        Wl[L] = (const float*)d_in[3 + 5 * L + 0];
        bl[L] = (const float*)d_in[3 + 5 * L + 1];
        Wr[L] = (const float*)d_in[3 + 5 * L + 2];
        gm[L] = (const float*)d_in[3 + 5 * L + 3];
        bt[L] = (const float*)d_in[3 + 5 * L + 4];
    }

    const int n = in_sizes[0] / NFEAT;
    const int ne = in_sizes[1] / 2;
    const int ngraphs = out_size / NCAT;
    const int* src = ei;
    const int* dstp = ei + ne;

    char* wsb = (char*)d_ws;
    size_t off = 0;
    float* agg = (float*)(wsb + off);   off += (size_t)n * NFEAT * 4;
    float* bufA = (float*)(wsb + off);  off += (size_t)n * NFEAT * 4;
    float* bufB = (float*)(wsb + off);  off += (size_t)n * NFEAT * 4;
    unsigned short* xbA = (unsigned short*)(wsb + off); off += (size_t)n * NFEAT * 2;
    unsigned short* xbB = (unsigned short*)(wsb + off); off += (size_t)n * NFEAT * 2;
    int* csr_src = (int*)(wsb + off);   off += (size_t)ne * 4;
    int* row_start = (int*)(wsb + off); off += (size_t)n * 4;
    int* cursor = (int*)(wsb + off);    off += (size_t)n * 4;
    int* deg = (int*)(wsb + off);       off += (size_t)n * 4;
    float* recip = (float*)(wsb + off); off += (size_t)n * 4;
    float* stats = (float*)(wsb + off); off += 128 * 4;
    float* pool = (float*)(wsb + off);  off += (size_t)ngraphs * NCAT * 4;
    float* cntf = (float*)(wsb + off);  off += (size_t)ngraphs * 4;

    hipMemsetAsync(deg, 0, (size_t)n * sizeof(int), stream);
    hipMemsetAsync(cntf, 0, (size_t)ngraphs * sizeof(float), stream);
    hipMemsetAsync(pool, 0, (size_t)ngraphs * NCAT * sizeof(float), stream);

    deg_kernel<<<(ne + 255) / 256, 256, 0, stream>>>(dstp, deg, ne);
    cnt_kernel<<<(n + 255) / 256, 256, 0, stream>>>(batch, cntf, n);
    recip_kernel<<<(n + 255) / 256, 256, 0, stream>>>(deg, recip, n);
    scan_kernel<<<1, 1024, 0, stream>>>(deg, row_start, cursor, n);
    fill_kernel<<<(ne + 255) / 256, 256, 0, stream>>>(src, dstp, cursor, csr_src, ne);
    cvt_kernel<<<((n * NFEAT / 4) + 255) / 256, 256, 0, stream>>>(x, xbA, n * NFEAT / 4);

    const unsigned short* gin[3] = {xbA, xbB, xbA};
    unsigned short* gout[3] = {xbB, xbA, nullptr};
    const float* lin_in = x;
    float* lout[3] = {bufA, bufB, bufA};
    for (int L = 0; L < 3; ++L) {
        float* dbuf = lout[L];
        hipMemsetAsync(stats, 0, 128 * sizeof(float), stream);
        gather_kernel<<<(n + 3) / 4, 256, 0, stream>>>(gin[L], row_start, deg, recip,
                                                       csr_src, agg, n);
        lin_kernel<<<1024, 256, 0, stream>>>(agg, lin_in, Wl[L], bl[L], Wr[L], dbuf, stats, n);
        bn_kernel<<<(n + BN_NODES - 1) / BN_NODES, 256, 0, stream>>>(
            dbuf, gout[L], stats, gm[L], bt[L], batch, pool, L * NFEAT, n);
        lin_in = dbuf;
    }
    final_kernel<<<(out_size + 255) / 256, 256, 0, stream>>>(pool, cntf, (float*)d_out, out_size);
}

// Round 4
// 982.772 us; speedup vs baseline: 2.1431x; 2.1431x over previous
//
#include <hip/hip_runtime.h>

#define NFEAT 64
#define NCAT 192
#define BN_NODES 32
#define BN_SPAN 8

typedef float f32x4 __attribute__((ext_vector_type(4)));
typedef short bf16x8 __attribute__((ext_vector_type(8)));

__device__ __forceinline__ float bf2f(unsigned int u16) {
    union { unsigned int i; float f; } c; c.i = u16 << 16; return c.f;
}
__device__ __forceinline__ unsigned short f2bf(float f) {
    union { float f; unsigned int i; } c; c.f = f;
    unsigned int r = c.i + 0x7fffu + ((c.i >> 16) & 1u);
    return (unsigned short)(r >> 16);
}

__global__ void deg_kernel(const int* __restrict__ dst, int* __restrict__ deg, int nedges) {
    int e = blockIdx.x * blockDim.x + threadIdx.x;
    if (e < nedges) atomicAdd(&deg[dst[e]], 1);
}

__global__ void cnt_kernel(const int* __restrict__ batch, float* __restrict__ cnt, int n) {
    int i = blockIdx.x * blockDim.x + threadIdx.x;
    if (i < n) atomicAdd(&cnt[batch[i]], 1.0f);
}

__global__ void cvt_kernel(const float* __restrict__ x, unsigned short* __restrict__ xb, int total4) {
    int t = blockIdx.x * blockDim.x + threadIdx.x;
    if (t < total4) {
        float4 v = reinterpret_cast<const float4*>(x)[t];
        ushort4 o;
        o.x = f2bf(v.x); o.y = f2bf(v.y); o.z = f2bf(v.z); o.w = f2bf(v.w);
        reinterpret_cast<ushort4*>(xb)[t] = o;
    }
}

// Convert the 3 layers' [Wl|Wr] into wcat[L][feat][128] bf16 (k<64 from Wl, k>=64 from Wr).
__global__ void wprep_kernel(const float* __restrict__ Wl0, const float* __restrict__ Wr0,
                             const float* __restrict__ Wl1, const float* __restrict__ Wr1,
                             const float* __restrict__ Wl2, const float* __restrict__ Wr2,
                             unsigned short* __restrict__ wcat) {
    int t = blockIdx.x * blockDim.x + threadIdx.x;
    if (t >= 3 * 64 * 128) return;
    int L = t >> 13;
    int r = t & 8191;
    int f = r >> 7, k = r & 127;
    const float* Wl = (L == 0) ? Wl0 : (L == 1) ? Wl1 : Wl2;
    const float* Wr = (L == 0) ? Wr0 : (L == 1) ? Wr1 : Wr2;
    float v = (k < 64) ? Wl[f * 64 + k] : Wr[f * 64 + (k - 64)];
    wcat[t] = f2bf(v);
}

// Single-block exclusive scan over deg -> row_start (and cursor copy).
__global__ __launch_bounds__(1024) void scan_kernel(const int* __restrict__ deg,
                                                    int* __restrict__ row_start,
                                                    int* __restrict__ cursor, int n) {
    __shared__ int wtot[16];
    __shared__ int woff[16];
    __shared__ int carry_s;
    int tid = threadIdx.x, lane = tid & 63, wid = tid >> 6;
    if (tid == 0) carry_s = 0;
    __syncthreads();
    for (int base = 0; base < n; base += 1024) {
        int i = base + tid;
        int v = (i < n) ? deg[i] : 0;
        int incl = v;
#pragma unroll
        for (int off = 1; off < 64; off <<= 1) {
            int t = __shfl_up(incl, off);
            if (lane >= off) incl += t;
        }
        if (lane == 63) wtot[wid] = incl;
        __syncthreads();
        if (wid == 0) {
            int wv = (lane < 16) ? wtot[lane] : 0;
            int winc = wv;
#pragma unroll
            for (int off = 1; off < 16; off <<= 1) {
                int t = __shfl_up(winc, off);
                if (lane >= off) winc += t;
            }
            if (lane < 16) woff[lane] = winc - wv;
        }
        __syncthreads();
        int carry = carry_s;
        int excl = carry + woff[wid] + (incl - v);
        if (i < n) { row_start[i] = excl; cursor[i] = excl; }
        int ctot = woff[15] + wtot[15];
        __syncthreads();
        if (tid == 0) carry_s = carry + ctot;
        __syncthreads();
    }
}

__global__ void fill_kernel(const int* __restrict__ src, const int* __restrict__ dst,
                            int* __restrict__ cursor, int* __restrict__ csr_src, int ne) {
    int e = blockIdx.x * blockDim.x + threadIdx.x;
    if (e < ne) {
        int d = dst[e];
        int pos = atomicAdd(&cursor[d], 1);
        csr_src[pos] = src[e];
    }
}

// Wave-per-node CSR mean-gather from bf16 features. 8 neighbors in flight:
// lane = (slot g = lane>>3, feature-octet q = lane&7), 16B loads, butterfly reduce.
// Writes bf16 agg row. No LDS -> high occupancy for latency hiding.
__global__ __launch_bounds__(256, 8) void gather_kernel(
    const unsigned short* __restrict__ xb, const int* __restrict__ row_start,
    const int* __restrict__ deg, const int* __restrict__ csr_src,
    unsigned short* __restrict__ aggb, int n) {
    int lane = threadIdx.x & 63;
    int i = (blockIdx.x * blockDim.x + threadIdx.x) >> 6;
    if (i >= n) return;
    int rs = row_start[i], dg = deg[i];
    int g = lane >> 3, q = lane & 7;
    float av[8];
#pragma unroll
    for (int c = 0; c < 8; ++c) av[c] = 0.0f;

    for (int base = 0; base < dg; base += 64) {
        int cnt = min(dg - base, 64);
        int myidx = (lane < cnt) ? csr_src[rs + base + lane] : 0;
        for (int p = 0; p < cnt; p += 8) {
            int slot = p + g;
            int nb = __shfl(myidx, slot);
            if (slot < cnt) {
                const uint4 v = *reinterpret_cast<const uint4*>(xb + (size_t)nb * NFEAT + q * 8);
                av[0] += bf2f(v.x & 0xffffu);
                av[1] += bf2f(v.x >> 16);
                av[2] += bf2f(v.y & 0xffffu);
                av[3] += bf2f(v.y >> 16);
                av[4] += bf2f(v.z & 0xffffu);
                av[5] += bf2f(v.z >> 16);
                av[6] += bf2f(v.w & 0xffffu);
                av[7] += bf2f(v.w >> 16);
            }
        }
    }
#pragma unroll
    for (int c = 0; c < 8; ++c) {
        av[c] += __shfl_xor(av[c], 8);
        av[c] += __shfl_xor(av[c], 16);
        av[c] += __shfl_xor(av[c], 32);
    }
    if (g == 0) {
        float r = 1.0f / (float)max(dg, 1);
        uint4 o;
        o.x = (unsigned)f2bf(av[0] * r) | ((unsigned)f2bf(av[1] * r) << 16);
        o.y = (unsigned)f2bf(av[2] * r) | ((unsigned)f2bf(av[3] * r) << 16);
        o.z = (unsigned)f2bf(av[4] * r) | ((unsigned)f2bf(av[5] * r) << 16);
        o.w = (unsigned)f2bf(av[6] * r) | ((unsigned)f2bf(av[7] * r) << 16);
        *reinterpret_cast<uint4*>(aggb + (size_t)i * NFEAT + q * 8) = o;
    }
}

// MFMA linear: h[n x 64] = [aggb | xb] @ wcat^T + bl. One wave = 16-node x 64-feat tile.
// A-frag: row = lane&15 (node), k = (lane>>4)*8 + j (contiguous 16B loads).
// B-frag: row = lane&15 (feat), k likewise, from wcat[feat][128] rows.
// C/D: col = lane&15 (feat), row = (lane>>4)*4 + reg (node)  [verified layout].
// Accumulates BN sum/sumsq via shfl_xor(16/32) + 8 atomics per wave.
__global__ __launch_bounds__(256) void lin_mfma_kernel(
    const unsigned short* __restrict__ aggb, const unsigned short* __restrict__ xb,
    const unsigned short* __restrict__ wcat, const float* __restrict__ bl,
    float* __restrict__ h, float* __restrict__ stats, int n) {
    int lane = threadIdx.x & 63;
    int wid = (blockIdx.x * blockDim.x + threadIdx.x) >> 6;
    int nw = (gridDim.x * blockDim.x) >> 6;
    int r16 = lane & 15, kb = lane >> 4;

    bf16x8 bfrag[4][4];
#pragma unroll
    for (int kt = 0; kt < 4; ++kt)
#pragma unroll
        for (int nt = 0; nt < 4; ++nt)
            bfrag[kt][nt] = *reinterpret_cast<const bf16x8*>(
                wcat + (size_t)(nt * 16 + r16) * 128 + kt * 32 + kb * 8);

    float blj[4];
#pragma unroll
    for (int nt = 0; nt < 4; ++nt) blj[nt] = bl[nt * 16 + r16];

    float s1[4] = {0.f, 0.f, 0.f, 0.f}, s2[4] = {0.f, 0.f, 0.f, 0.f};
    int ntiles = (n + 15) >> 4;
    for (int t = wid; t < ntiles; t += nw) {
        int nbase = t << 4;
        int node = nbase + r16;
        size_t arow = (size_t)min(node, n - 1) * NFEAT;
        bf16x8 af[4];
        af[0] = *reinterpret_cast<const bf16x8*>(aggb + arow + kb * 8);
        af[1] = *reinterpret_cast<const bf16x8*>(aggb + arow + 32 + kb * 8);
        af[2] = *reinterpret_cast<const bf16x8*>(xb + arow + kb * 8);
        af[3] = *reinterpret_cast<const bf16x8*>(xb + arow + 32 + kb * 8);

        f32x4 acc[4] = {{0.f,0.f,0.f,0.f},{0.f,0.f,0.f,0.f},{0.f,0.f,0.f,0.f},{0.f,0.f,0.f,0.f}};
#pragma unroll
        for (int kt = 0; kt < 4; ++kt) {
#pragma unroll
            for (int nt = 0; nt < 4; ++nt)
                acc[nt] = __builtin_amdgcn_mfma_f32_16x16x32_bf16(af[kt], bfrag[kt][nt], acc[nt], 0, 0, 0);
        }
#pragma unroll
        for (int nt = 0; nt < 4; ++nt) {
#pragma unroll
            for (int reg = 0; reg < 4; ++reg) {
                int ni = nbase + kb * 4 + reg;
                if (ni < n) {
                    float v = acc[nt][reg] + blj[nt];
                    h[(size_t)ni * NFEAT + nt * 16 + r16] = v;
                    s1[nt] += v;
                    s2[nt] += v * v;
                }
            }
        }
    }
#pragma unroll
    for (int nt = 0; nt < 4; ++nt) {
        s1[nt] += __shfl_xor(s1[nt], 16); s1[nt] += __shfl_xor(s1[nt], 32);
        s2[nt] += __shfl_xor(s2[nt], 16); s2[nt] += __shfl_xor(s2[nt], 32);
    }
    if (lane < 16) {
#pragma unroll
        for (int nt = 0; nt < 4; ++nt) {
            atomicAdd(&stats[nt * 16 + lane], s1[nt]);
            atomicAdd(&stats[64 + nt * 16 + lane], s2[nt]);
        }
    }
}

// BN (training stats) + ReLU; emits bf16 next-layer features (if hbf) and pool
// accumulation via LDS (batch sorted). h is read-only (post-BN fp32 never needed).
__global__ __launch_bounds__(256) void bn_kernel(
    const float* __restrict__ h, unsigned short* __restrict__ hbf,
    const float* __restrict__ stats,
    const float* __restrict__ g, const float* __restrict__ b,
    const int* __restrict__ batch, float* __restrict__ pool,
    int colbase, int n) {
    __shared__ float pl[BN_SPAN][64];
    __shared__ int gmin_s, span_s;
    int tid = threadIdx.x;
    int j = tid & 63;
    int sub = tid >> 6;
    int nbase = blockIdx.x * BN_NODES;
    if (nbase >= n) return;

    if (tid == 0) {
        int last = min(nbase + BN_NODES, n) - 1;
        gmin_s = batch[nbase];
        span_s = batch[last] - gmin_s + 1;
    }
    __syncthreads();
    int gmin = gmin_s, span = span_s;
    bool use_lds = (span <= BN_SPAN);
    if (use_lds) {
        for (int t = tid; t < span * 64; t += 256) ((float*)pl)[t] = 0.0f;
    }
    __syncthreads();

    float invn = 1.0f / (float)n;
    float mu = stats[j] * invn;
    float var = stats[64 + j] * invn - mu * mu;
    float sc = rsqrtf(var + 1e-5f) * g[j];
    float bb = b[j];

    for (int r = sub; r < BN_NODES; r += 4) {
        int i = nbase + r;
        if (i >= n) break;
        size_t idx = (size_t)i * NFEAT + j;
        float v = fmaxf((h[idx] - mu) * sc + bb, 0.0f);
        if (hbf) hbf[idx] = f2bf(v);
        int gi = batch[i];
        if (use_lds) atomicAdd(&pl[gi - gmin][j], v);
        else atomicAdd(&pool[(size_t)gi * NCAT + colbase + j], v);
    }
    __syncthreads();
    if (use_lds) {
        for (int t = tid; t < span * 64; t += 256) {
            int s = t >> 6, j2 = t & 63;
            float v = pl[s][j2];
            if (v != 0.0f) atomicAdd(&pool[(size_t)(gmin + s) * NCAT + colbase + j2], v);
        }
    }
}

__global__ void final_kernel(const float* __restrict__ pool, const float* __restrict__ cnt,
                             float* __restrict__ out, int total) {
    int t = blockIdx.x * blockDim.x + threadIdx.x;
    if (t >= total) return;
    int gidx = t / NCAT;
    out[t] = pool[t] / fmaxf(cnt[gidx], 1.0f);
}

extern "C" void kernel_launch(void* const* d_in, const int* in_sizes, int n_in,
                              void* d_out, int out_size, void* d_ws, size_t ws_size,
                              hipStream_t stream) {
    const float* x = (const float*)d_in[0];
    const int* ei = (const int*)d_in[1];
    const int* batch = (const int*)d_in[2];

    const float* Wl[3], *bl[3], *Wr[3], *gm[3], *bt[3];
    for (int L = 0; L < 3; ++L) {
        Wl[L] = (const float*)d_in[3 + 5 * L + 0];
        bl[L] = (const float*)d_in[3 + 5 * L + 1];
        Wr[L] = (const float*)d_in[3 + 5 * L + 2];
        gm[L] = (const float*)d_in[3 + 5 * L + 3];
        bt[L] = (const float*)d_in[3 + 5 * L + 4];
    }

    const int n = in_sizes[0] / NFEAT;
    const int ne = in_sizes[1] / 2;
    const int ngraphs = out_size / NCAT;
    const int* src = ei;
    const int* dstp = ei + ne;

    char* wsb = (char*)d_ws;
    size_t off = 0;
    float* h = (float*)(wsb + off);      off += (size_t)n * NFEAT * 4;
    unsigned short* aggb = (unsigned short*)(wsb + off); off += (size_t)n * NFEAT * 2;
    unsigned short* xbA = (unsigned short*)(wsb + off);  off += (size_t)n * NFEAT * 2;
    unsigned short* xbB = (unsigned short*)(wsb + off);  off += (size_t)n * NFEAT * 2;
    unsigned short* wcat = (unsigned short*)(wsb + off); off += 3 * 64 * 128 * 2;
    int* csr_src = (int*)(wsb + off);    off += (size_t)ne * 4;
    int* row_start = (int*)(wsb + off);  off += (size_t)n * 4;
    int* cursor = (int*)(wsb + off);     off += (size_t)n * 4;
    int* deg = (int*)(wsb + off);        off += (size_t)n * 4;
    float* stats = (float*)(wsb + off);  off += 128 * 4;
    float* pool = (float*)(wsb + off);   off += (size_t)ngraphs * NCAT * 4;
    float* cntf = (float*)(wsb + off);   off += (size_t)ngraphs * 4;

    hipMemsetAsync(deg, 0, (size_t)n * sizeof(int), stream);
    hipMemsetAsync(cntf, 0, (size_t)ngraphs * sizeof(float), stream);
    hipMemsetAsync(pool, 0, (size_t)ngraphs * NCAT * sizeof(float), stream);

    deg_kernel<<<(ne + 255) / 256, 256, 0, stream>>>(dstp, deg, ne);
    cnt_kernel<<<(n + 255) / 256, 256, 0, stream>>>(batch, cntf, n);
    scan_kernel<<<1, 1024, 0, stream>>>(deg, row_start, cursor, n);
    fill_kernel<<<(ne + 255) / 256, 256, 0, stream>>>(src, dstp, cursor, csr_src, ne);
    cvt_kernel<<<((n * NFEAT / 4) + 255) / 256, 256, 0, stream>>>(x, xbA, n * NFEAT / 4);
    wprep_kernel<<<(3 * 64 * 128 + 255) / 256, 256, 0, stream>>>(
        Wl[0], Wr[0], Wl[1], Wr[1], Wl[2], Wr[2], wcat);

    const unsigned short* gin[3] = {xbA, xbB, xbA};
    unsigned short* gout[3] = {xbB, xbA, nullptr};
    for (int L = 0; L < 3; ++L) {
        hipMemsetAsync(stats, 0, 128 * sizeof(float), stream);
        gather_kernel<<<(n + 3) / 4, 256, 0, stream>>>(gin[L], row_start, deg, csr_src, aggb, n);
        lin_mfma_kernel<<<1024, 256, 0, stream>>>(aggb, gin[L], wcat + (size_t)L * 8192,
                                                  bl[L], h, stats, n);
        bn_kernel<<<(n + BN_NODES - 1) / BN_NODES, 256, 0, stream>>>(
            h, gout[L], stats, gm[L], bt[L], batch, pool, L * NFEAT, n);
    }
    final_kernel<<<(out_size + 255) / 256, 256, 0, stream>>>(pool, cntf, (float*)d_out, out_size);
}

// Round 5
// 751.269 us; speedup vs baseline: 2.8035x; 1.3081x over previous
//
#include <hip/hip_runtime.h>

#define NFEAT 64
#define NCAT 192
#define BN_NODES 32
#define BN_SPAN 8
#define NBLK 128
#define P4CAP 4608

typedef float f32x4 __attribute__((ext_vector_type(4)));
typedef short bf16x8 __attribute__((ext_vector_type(8)));

__device__ __forceinline__ float bf2f(unsigned int u16) {
    union { unsigned int i; float f; } c; c.i = u16 << 16; return c.f;
}
__device__ __forceinline__ unsigned short f2bf(float f) {
    union { float f; unsigned int i; } c; c.f = f;
    unsigned int r = c.i + 0x7fffu + ((c.i >> 16) & 1u);
    return (unsigned short)(r >> 16);
}

__global__ void cnt_kernel(const int* __restrict__ batch, float* __restrict__ cnt, int n) {
    int i = blockIdx.x * blockDim.x + threadIdx.x;
    if (i < n) atomicAdd(&cnt[batch[i]], 1.0f);
}

__global__ void cvt_kernel(const float* __restrict__ x, unsigned short* __restrict__ xb, int total4) {
    int t = blockIdx.x * blockDim.x + threadIdx.x;
    if (t < total4) {
        float4 v = reinterpret_cast<const float4*>(x)[t];
        ushort4 o;
        o.x = f2bf(v.x); o.y = f2bf(v.y); o.z = f2bf(v.z); o.w = f2bf(v.w);
        reinterpret_cast<ushort4*>(xb)[t] = o;
    }
}

__global__ void wprep_kernel(const float* __restrict__ Wl0, const float* __restrict__ Wr0,
                             const float* __restrict__ Wl1, const float* __restrict__ Wr1,
                             const float* __restrict__ Wl2, const float* __restrict__ Wr2,
                             unsigned short* __restrict__ wcat) {
    int t = blockIdx.x * blockDim.x + threadIdx.x;
    if (t >= 3 * 64 * 128) return;
    int L = t >> 13;
    int r = t & 8191;
    int f = r >> 7, k = r & 127;
    const float* Wl = (L == 0) ? Wl0 : (L == 1) ? Wl1 : Wl2;
    const float* Wr = (L == 0) ? Wr0 : (L == 1) ? Wr1 : Wr2;
    float v = (k < 64) ? Wl[f * 64 + k] : Wr[f * 64 + (k - 64)];
    wcat[t] = f2bf(v);
}

// ---- CSR build as two-level counting sort (bucket = dst >> 8) ----

// P1: per-block histogram over buckets; each block owns a contiguous edge chunk.
__global__ __launch_bounds__(256) void hist_kernel(const int* __restrict__ dst,
                                                   int* __restrict__ C, int ne, int nbuck) {
    __shared__ int hist[1024];
    int blk = blockIdx.x, tid = threadIdx.x;
    for (int t = tid; t < nbuck; t += 256) hist[t] = 0;
    __syncthreads();
    int chunk = (ne + NBLK - 1) / NBLK;
    int s = blk * chunk, e_end = min(s + chunk, ne);
    for (int e = s + tid; e < e_end; e += 256) atomicAdd(&hist[dst[e] >> 8], 1);
    __syncthreads();
    for (int t = tid; t < nbuck; t += 256) C[t * NBLK + blk] = hist[t];
}

// P2a: exclusive scan each bucket's column of per-block counts (128 values).
__global__ __launch_bounds__(128) void colscan_kernel(const int* __restrict__ C,
                                                      int* __restrict__ Cs,
                                                      int* __restrict__ coltot) {
    __shared__ int wt[2];
    int b = blockIdx.x, t = threadIdx.x;
    int v = C[b * NBLK + t];
    int lane = t & 63, w = t >> 6;
    int incl = v;
#pragma unroll
    for (int off = 1; off < 64; off <<= 1) { int u = __shfl_up(incl, off); if (lane >= off) incl += u; }
    if (lane == 63) wt[w] = incl;
    __syncthreads();
    int excl = incl - v + ((w == 1) ? wt[0] : 0);
    Cs[b * NBLK + t] = excl;
    if (t == NBLK - 1) coltot[b] = excl + v;
}

// P2b: exclusive scan of bucket totals -> bucket_base (also the CSR region base).
__global__ __launch_bounds__(1024) void topscan_kernel(const int* __restrict__ coltot,
                                                       int* __restrict__ bucket_base,
                                                       int nbuck, int ne) {
    __shared__ int a[1024];
    int t = threadIdx.x;
    int v = (t < nbuck) ? coltot[t] : 0;
    a[t] = v;
    __syncthreads();
    for (int off = 1; off < 1024; off <<= 1) {
        int u = (t >= off) ? a[t - off] : 0;
        __syncthreads();
        a[t] += u;
        __syncthreads();
    }
    if (t < nbuck) bucket_base[t] = a[t] - v;
    if (t == 0) bucket_base[nbuck] = ne;
}

// P3: scatter packed (dstlow<<24)|src into bucket-grouped ebuf; each (block,bucket)
// sub-range is private and contiguous -> write-combining friendly.
__global__ __launch_bounds__(256) void scatter3_kernel(const int* __restrict__ src,
                                                       const int* __restrict__ dst,
                                                       const int* __restrict__ Cs,
                                                       const int* __restrict__ bucket_base,
                                                       unsigned int* __restrict__ ebuf,
                                                       int ne, int nbuck) {
    __shared__ int cur[1024];
    int blk = blockIdx.x, tid = threadIdx.x;
    for (int t = tid; t < nbuck; t += 256) cur[t] = bucket_base[t] + Cs[t * NBLK + blk];
    __syncthreads();
    int chunk = (ne + NBLK - 1) / NBLK;
    int s = blk * chunk, e_end = min(s + chunk, ne);
    for (int e = s + tid; e < e_end; e += 256) {
        int sv = src[e], dv = dst[e];
        int b = dv >> 8;
        int r = atomicAdd(&cur[b], 1);
        ebuf[r] = (unsigned)sv | ((unsigned)(dv & 255) << 24);
    }
}

// P4: one block per bucket. Local deg count + scan -> row_start; LDS cursor fill
// -> csr_src (coalesced, bucket-local). Replaces deg/scan/fill kernels.
__global__ __launch_bounds__(256) void bucketfill_kernel(const unsigned int* __restrict__ ebuf,
                                                         const int* __restrict__ bucket_base,
                                                         int* __restrict__ row_start,
                                                         int* __restrict__ csr_src,
                                                         int n, int ne) {
    __shared__ unsigned int ed[P4CAP];
    __shared__ int deg_l[256];
    __shared__ int cur_l[256];
    __shared__ int wsum[4];
    int b = blockIdx.x, tid = threadIdx.x;
    int s = bucket_base[b];
    int cnt = bucket_base[b + 1] - s;
    deg_l[tid] = 0;
    __syncthreads();
    for (int t = tid; t < cnt; t += 256) {
        unsigned int e = ebuf[s + t];
        if (t < P4CAP) ed[t] = e;
        atomicAdd(&deg_l[e >> 24], 1);
    }
    __syncthreads();
    int v = deg_l[tid];
    int lane = tid & 63, w = tid >> 6;
    int incl = v;
#pragma unroll
    for (int off = 1; off < 64; off <<= 1) { int u = __shfl_up(incl, off); if (lane >= off) incl += u; }
    if (lane == 63) wsum[w] = incl;
    __syncthreads();
    int wofs = 0;
    for (int k = 0; k < w; ++k) wofs += wsum[k];
    int excl = wofs + incl - v;
    int node = b * 256 + tid;
    if (node < n) row_start[node] = s + excl;
    if (b == 0 && tid == 0) row_start[n] = ne;
    cur_l[tid] = excl;
    __syncthreads();
    for (int t = tid; t < cnt; t += 256) {
        unsigned int e = (t < P4CAP) ? ed[t] : ebuf[s + t];
        int d = e >> 24;
        int r = atomicAdd(&cur_l[d], 1);
        csr_src[s + r] = (int)(e & 0xFFFFFFu);
    }
}

// Wave-per-node CSR mean-gather from bf16 features. 16 neighbors in flight per
// iteration (two guarded 16B loads issued before consumption). deg from row_start.
__global__ __launch_bounds__(256, 8) void gather_kernel(
    const unsigned short* __restrict__ xb, const int* __restrict__ row_start,
    const int* __restrict__ csr_src, unsigned short* __restrict__ aggb, int n) {
    int lane = threadIdx.x & 63;
    int i = (blockIdx.x * blockDim.x + threadIdx.x) >> 6;
    if (i >= n) return;
    int rs = row_start[i];
    int dg = row_start[i + 1] - rs;
    int g = lane >> 3, q = lane & 7;
    const unsigned short* xq = xb + q * 8;
    float av[8];
#pragma unroll
    for (int c = 0; c < 8; ++c) av[c] = 0.0f;

    for (int base = 0; base < dg; base += 64) {
        int cnt = min(dg - base, 64);
        int myidx = (lane < cnt) ? csr_src[rs + base + lane] : 0;
        for (int p = 0; p < cnt; p += 16) {
            int s0 = p + g, s1 = p + g + 8;
            int nb0 = __shfl(myidx, s0);
            int nb1 = __shfl(myidx, s1);
            bool a0 = s0 < cnt, a1 = s1 < cnt;
            uint4 v0, v1;
            if (a0) v0 = *reinterpret_cast<const uint4*>(xq + (size_t)nb0 * NFEAT);
            if (a1) v1 = *reinterpret_cast<const uint4*>(xq + (size_t)nb1 * NFEAT);
            if (a0) {
                av[0] += bf2f(v0.x & 0xffffu); av[1] += bf2f(v0.x >> 16);
                av[2] += bf2f(v0.y & 0xffffu); av[3] += bf2f(v0.y >> 16);
                av[4] += bf2f(v0.z & 0xffffu); av[5] += bf2f(v0.z >> 16);
                av[6] += bf2f(v0.w & 0xffffu); av[7] += bf2f(v0.w >> 16);
            }
            if (a1) {
                av[0] += bf2f(v1.x & 0xffffu); av[1] += bf2f(v1.x >> 16);
                av[2] += bf2f(v1.y & 0xffffu); av[3] += bf2f(v1.y >> 16);
                av[4] += bf2f(v1.z & 0xffffu); av[5] += bf2f(v1.z >> 16);
                av[6] += bf2f(v1.w & 0xffffu); av[7] += bf2f(v1.w >> 16);
            }
        }
    }
#pragma unroll
    for (int c = 0; c < 8; ++c) {
        av[c] += __shfl_xor(av[c], 8);
        av[c] += __shfl_xor(av[c], 16);
        av[c] += __shfl_xor(av[c], 32);
    }
    if (g == 0) {
        float r = 1.0f / (float)max(dg, 1);
        uint4 o;
        o.x = (unsigned)f2bf(av[0] * r) | ((unsigned)f2bf(av[1] * r) << 16);
        o.y = (unsigned)f2bf(av[2] * r) | ((unsigned)f2bf(av[3] * r) << 16);
        o.z = (unsigned)f2bf(av[4] * r) | ((unsigned)f2bf(av[5] * r) << 16);
        o.w = (unsigned)f2bf(av[6] * r) | ((unsigned)f2bf(av[7] * r) << 16);
        *reinterpret_cast<uint4*>(aggb + (size_t)i * NFEAT + q * 8) = o;
    }
}

// MFMA linear: h[n x 64] = [aggb | xb] @ wcat^T + bl. One wave = 16-node x 64-feat tile.
__global__ __launch_bounds__(256) void lin_mfma_kernel(
    const unsigned short* __restrict__ aggb, const unsigned short* __restrict__ xb,
    const unsigned short* __restrict__ wcat, const float* __restrict__ bl,
    float* __restrict__ h, float* __restrict__ stats, int n) {
    int lane = threadIdx.x & 63;
    int wid = (blockIdx.x * blockDim.x + threadIdx.x) >> 6;
    int nw = (gridDim.x * blockDim.x) >> 6;
    int r16 = lane & 15, kb = lane >> 4;

    bf16x8 bfrag[4][4];
#pragma unroll
    for (int kt = 0; kt < 4; ++kt)
#pragma unroll
        for (int nt = 0; nt < 4; ++nt)
            bfrag[kt][nt] = *reinterpret_cast<const bf16x8*>(
                wcat + (size_t)(nt * 16 + r16) * 128 + kt * 32 + kb * 8);

    float blj[4];
#pragma unroll
    for (int nt = 0; nt < 4; ++nt) blj[nt] = bl[nt * 16 + r16];

    float s1[4] = {0.f, 0.f, 0.f, 0.f}, s2[4] = {0.f, 0.f, 0.f, 0.f};
    int ntiles = (n + 15) >> 4;
    for (int t = wid; t < ntiles; t += nw) {
        int nbase = t << 4;
        int node = nbase + r16;
        size_t arow = (size_t)min(node, n - 1) * NFEAT;
        bf16x8 af[4];
        af[0] = *reinterpret_cast<const bf16x8*>(aggb + arow + kb * 8);
        af[1] = *reinterpret_cast<const bf16x8*>(aggb + arow + 32 + kb * 8);
        af[2] = *reinterpret_cast<const bf16x8*>(xb + arow + kb * 8);
        af[3] = *reinterpret_cast<const bf16x8*>(xb + arow + 32 + kb * 8);

        f32x4 acc[4] = {{0.f,0.f,0.f,0.f},{0.f,0.f,0.f,0.f},{0.f,0.f,0.f,0.f},{0.f,0.f,0.f,0.f}};
#pragma unroll
        for (int kt = 0; kt < 4; ++kt) {
#pragma unroll
            for (int nt = 0; nt < 4; ++nt)
                acc[nt] = __builtin_amdgcn_mfma_f32_16x16x32_bf16(af[kt], bfrag[kt][nt], acc[nt], 0, 0, 0);
        }
#pragma unroll
        for (int nt = 0; nt < 4; ++nt) {
#pragma unroll
            for (int reg = 0; reg < 4; ++reg) {
                int ni = nbase + kb * 4 + reg;
                if (ni < n) {
                    float v = acc[nt][reg] + blj[nt];
                    h[(size_t)ni * NFEAT + nt * 16 + r16] = v;
                    s1[nt] += v;
                    s2[nt] += v * v;
                }
            }
        }
    }
#pragma unroll
    for (int nt = 0; nt < 4; ++nt) {
        s1[nt] += __shfl_xor(s1[nt], 16); s1[nt] += __shfl_xor(s1[nt], 32);
        s2[nt] += __shfl_xor(s2[nt], 16); s2[nt] += __shfl_xor(s2[nt], 32);
    }
    if (lane < 16) {
#pragma unroll
        for (int nt = 0; nt < 4; ++nt) {
            atomicAdd(&stats[nt * 16 + lane], s1[nt]);
            atomicAdd(&stats[64 + nt * 16 + lane], s2[nt]);
        }
    }
}

// BN (training stats) + ReLU; emits bf16 next-layer features (if hbf) and pool
// accumulation via LDS (batch sorted).
__global__ __launch_bounds__(256) void bn_kernel(
    const float* __restrict__ h, unsigned short* __restrict__ hbf,
    const float* __restrict__ stats,
    const float* __restrict__ g, const float* __restrict__ b,
    const int* __restrict__ batch, float* __restrict__ pool,
    int colbase, int n) {
    __shared__ float pl[BN_SPAN][64];
    __shared__ int gmin_s, span_s;
    int tid = threadIdx.x;
    int j = tid & 63;
    int sub = tid >> 6;
    int nbase = blockIdx.x * BN_NODES;
    if (nbase >= n) return;

    if (tid == 0) {
        int last = min(nbase + BN_NODES, n) - 1;
        gmin_s = batch[nbase];
        span_s = batch[last] - gmin_s + 1;
    }
    __syncthreads();
    int gmin = gmin_s, span = span_s;
    bool use_lds = (span <= BN_SPAN);
    if (use_lds) {
        for (int t = tid; t < span * 64; t += 256) ((float*)pl)[t] = 0.0f;
    }
    __syncthreads();

    float invn = 1.0f / (float)n;
    float mu = stats[j] * invn;
    float var = stats[64 + j] * invn - mu * mu;
    float sc = rsqrtf(var + 1e-5f) * g[j];
    float bb = b[j];

    for (int r = sub; r < BN_NODES; r += 4) {
        int i = nbase + r;
        if (i >= n) break;
        size_t idx = (size_t)i * NFEAT + j;
        float v = fmaxf((h[idx] - mu) * sc + bb, 0.0f);
        if (hbf) hbf[idx] = f2bf(v);
        int gi = batch[i];
        if (use_lds) atomicAdd(&pl[gi - gmin][j], v);
        else atomicAdd(&pool[(size_t)gi * NCAT + colbase + j], v);
    }
    __syncthreads();
    if (use_lds) {
        for (int t = tid; t < span * 64; t += 256) {
            int s = t >> 6, j2 = t & 63;
            float v = pl[s][j2];
            if (v != 0.0f) atomicAdd(&pool[(size_t)(gmin + s) * NCAT + colbase + j2], v);
        }
    }
}

__global__ void final_kernel(const float* __restrict__ pool, const float* __restrict__ cnt,
                             float* __restrict__ out, int total) {
    int t = blockIdx.x * blockDim.x + threadIdx.x;
    if (t >= total) return;
    int gidx = t / NCAT;
    out[t] = pool[t] / fmaxf(cnt[gidx], 1.0f);
}

extern "C" void kernel_launch(void* const* d_in, const int* in_sizes, int n_in,
                              void* d_out, int out_size, void* d_ws, size_t ws_size,
                              hipStream_t stream) {
    const float* x = (const float*)d_in[0];
    const int* ei = (const int*)d_in[1];
    const int* batch = (const int*)d_in[2];

    const float* Wl[3], *bl[3], *Wr[3], *gm[3], *bt[3];
    for (int L = 0; L < 3; ++L) {
        Wl[L] = (const float*)d_in[3 + 5 * L + 0];
        bl[L] = (const float*)d_in[3 + 5 * L + 1];
        Wr[L] = (const float*)d_in[3 + 5 * L + 2];
        gm[L] = (const float*)d_in[3 + 5 * L + 3];
        bt[L] = (const float*)d_in[3 + 5 * L + 4];
    }

    const int n = in_sizes[0] / NFEAT;
    const int ne = in_sizes[1] / 2;
    const int ngraphs = out_size / NCAT;
    const int nbuck = (n + 255) >> 8;
    const int* src = ei;
    const int* dstp = ei + ne;

    char* wsb = (char*)d_ws;
    size_t off = 0;
    float* h = (float*)(wsb + off);      off += (size_t)n * NFEAT * 4;
    unsigned short* aggb = (unsigned short*)(wsb + off); off += (size_t)n * NFEAT * 2;
    unsigned short* xbA = (unsigned short*)(wsb + off);  off += (size_t)n * NFEAT * 2;
    unsigned short* xbB = (unsigned short*)(wsb + off);  off += (size_t)n * NFEAT * 2;
    unsigned short* wcat = (unsigned short*)(wsb + off); off += 3 * 64 * 128 * 2;
    int* csr_src = (int*)(wsb + off);    off += (size_t)ne * 4;
    unsigned int* ebuf = (unsigned int*)(wsb + off); off += (size_t)ne * 4;
    int* row_start = (int*)(wsb + off);  off += (size_t)(n + 1) * 4;
    int* C = (int*)(wsb + off);          off += (size_t)nbuck * NBLK * 4;
    int* Cs = (int*)(wsb + off);         off += (size_t)nbuck * NBLK * 4;
    int* coltot = (int*)(wsb + off);     off += (size_t)nbuck * 4;
    int* bucket_base = (int*)(wsb + off); off += (size_t)(nbuck + 1) * 4;
    float* stats = (float*)(wsb + off);  off += 128 * 4;
    float* pool = (float*)(wsb + off);   off += (size_t)ngraphs * NCAT * 4;
    float* cntf = (float*)(wsb + off);   off += (size_t)ngraphs * 4;

    hipMemsetAsync(cntf, 0, (size_t)ngraphs * sizeof(float), stream);
    hipMemsetAsync(pool, 0, (size_t)ngraphs * NCAT * sizeof(float), stream);

    hist_kernel<<<NBLK, 256, 0, stream>>>(dstp, C, ne, nbuck);
    colscan_kernel<<<nbuck, NBLK, 0, stream>>>(C, Cs, coltot);
    topscan_kernel<<<1, 1024, 0, stream>>>(coltot, bucket_base, nbuck, ne);
    scatter3_kernel<<<NBLK, 256, 0, stream>>>(src, dstp, Cs, bucket_base, ebuf, ne, nbuck);
    bucketfill_kernel<<<nbuck, 256, 0, stream>>>(ebuf, bucket_base, row_start, csr_src, n, ne);

    cnt_kernel<<<(n + 255) / 256, 256, 0, stream>>>(batch, cntf, n);
    cvt_kernel<<<((n * NFEAT / 4) + 255) / 256, 256, 0, stream>>>(x, xbA, n * NFEAT / 4);
    wprep_kernel<<<(3 * 64 * 128 + 255) / 256, 256, 0, stream>>>(
        Wl[0], Wr[0], Wl[1], Wr[1], Wl[2], Wr[2], wcat);

    const unsigned short* gin[3] = {xbA, xbB, xbA};
    unsigned short* gout[3] = {xbB, xbA, nullptr};
    for (int L = 0; L < 3; ++L) {
        hipMemsetAsync(stats, 0, 128 * sizeof(float), stream);
        gather_kernel<<<(n + 3) / 4, 256, 0, stream>>>(gin[L], row_start, csr_src, aggb, n);
        lin_mfma_kernel<<<1024, 256, 0, stream>>>(aggb, gin[L], wcat + (size_t)L * 8192,
                                                  bl[L], h, stats, n);
        bn_kernel<<<(n + BN_NODES - 1) / BN_NODES, 256, 0, stream>>>(
            h, gout[L], stats, gm[L], bt[L], batch, pool, L * NFEAT, n);
    }
    final_kernel<<<(out_size + 255) / 256, 256, 0, stream>>>(pool, cntf, (float*)d_out, out_size);
}

// Round 6
// 467.055 us; speedup vs baseline: 4.5095x; 1.6085x over previous
//
#include <hip/hip_runtime.h>

#define NFEAT 64
#define NCAT 192
#define BN_NODES 32
#define BN_SPAN 8
#define NBLK 128
#define P4CAP 4608

typedef float f32x4 __attribute__((ext_vector_type(4)));
typedef short bf16x8 __attribute__((ext_vector_type(8)));

__device__ __forceinline__ float bf2f(unsigned int u16) {
    union { unsigned int i; float f; } c; c.i = u16 << 16; return c.f;
}
__device__ __forceinline__ unsigned short f2bf(float f) {
    union { float f; unsigned int i; } c; c.f = f;
    unsigned int r = c.i + 0x7fffu + ((c.i >> 16) & 1u);
    return (unsigned short)(r >> 16);
}

__global__ void cnt_kernel(const int* __restrict__ batch, float* __restrict__ cnt, int n) {
    int i = blockIdx.x * blockDim.x + threadIdx.x;
    if (i < n) atomicAdd(&cnt[batch[i]], 1.0f);
}

__global__ void cvt_kernel(const float* __restrict__ x, unsigned short* __restrict__ xb, int total4) {
    int t = blockIdx.x * blockDim.x + threadIdx.x;
    if (t < total4) {
        float4 v = reinterpret_cast<const float4*>(x)[t];
        ushort4 o;
        o.x = f2bf(v.x); o.y = f2bf(v.y); o.z = f2bf(v.z); o.w = f2bf(v.w);
        reinterpret_cast<ushort4*>(xb)[t] = o;
    }
}

__global__ void wprep_kernel(const float* __restrict__ Wl0, const float* __restrict__ Wr0,
                             const float* __restrict__ Wl1, const float* __restrict__ Wr1,
                             const float* __restrict__ Wl2, const float* __restrict__ Wr2,
                             unsigned short* __restrict__ wcat) {
    int t = blockIdx.x * blockDim.x + threadIdx.x;
    if (t >= 3 * 64 * 128) return;
    int L = t >> 13;
    int r = t & 8191;
    int f = r >> 7, k = r & 127;
    const float* Wl = (L == 0) ? Wl0 : (L == 1) ? Wl1 : Wl2;
    const float* Wr = (L == 0) ? Wr0 : (L == 1) ? Wr1 : Wr2;
    float v = (k < 64) ? Wl[f * 64 + k] : Wr[f * 64 + (k - 64)];
    wcat[t] = f2bf(v);
}

// ---- CSR build as two-level counting sort (bucket = dst >> 8) ----

__global__ __launch_bounds__(256) void hist_kernel(const int* __restrict__ dst,
                                                   int* __restrict__ C, int ne, int nbuck) {
    __shared__ int hist[1024];
    int blk = blockIdx.x, tid = threadIdx.x;
    for (int t = tid; t < nbuck; t += 256) hist[t] = 0;
    __syncthreads();
    int chunk = (ne + NBLK - 1) / NBLK;
    int s = blk * chunk, e_end = min(s + chunk, ne);
    for (int e = s + tid; e < e_end; e += 256) atomicAdd(&hist[dst[e] >> 8], 1);
    __syncthreads();
    for (int t = tid; t < nbuck; t += 256) C[t * NBLK + blk] = hist[t];
}

__global__ __launch_bounds__(128) void colscan_kernel(const int* __restrict__ C,
                                                      int* __restrict__ Cs,
                                                      int* __restrict__ coltot) {
    __shared__ int wt[2];
    int b = blockIdx.x, t = threadIdx.x;
    int v = C[b * NBLK + t];
    int lane = t & 63, w = t >> 6;
    int incl = v;
#pragma unroll
    for (int off = 1; off < 64; off <<= 1) { int u = __shfl_up(incl, off); if (lane >= off) incl += u; }
    if (lane == 63) wt[w] = incl;
    __syncthreads();
    int excl = incl - v + ((w == 1) ? wt[0] : 0);
    Cs[b * NBLK + t] = excl;
    if (t == NBLK - 1) coltot[b] = excl + v;
}

__global__ __launch_bounds__(1024) void topscan_kernel(const int* __restrict__ coltot,
                                                       int* __restrict__ bucket_base,
                                                       int nbuck, int ne) {
    __shared__ int a[1024];
    int t = threadIdx.x;
    int v = (t < nbuck) ? coltot[t] : 0;
    a[t] = v;
    __syncthreads();
    for (int off = 1; off < 1024; off <<= 1) {
        int u = (t >= off) ? a[t - off] : 0;
        __syncthreads();
        a[t] += u;
        __syncthreads();
    }
    if (t < nbuck) bucket_base[t] = a[t] - v;
    if (t == 0) bucket_base[nbuck] = ne;
}

__global__ __launch_bounds__(256) void scatter3_kernel(const int* __restrict__ src,
                                                       const int* __restrict__ dst,
                                                       const int* __restrict__ Cs,
                                                       const int* __restrict__ bucket_base,
                                                       unsigned int* __restrict__ ebuf,
                                                       int ne, int nbuck) {
    __shared__ int cur[1024];
    int blk = blockIdx.x, tid = threadIdx.x;
    for (int t = tid; t < nbuck; t += 256) cur[t] = bucket_base[t] + Cs[t * NBLK + blk];
    __syncthreads();
    int chunk = (ne + NBLK - 1) / NBLK;
    int s = blk * chunk, e_end = min(s + chunk, ne);
    for (int e = s + tid; e < e_end; e += 256) {
        int sv = src[e], dv = dst[e];
        int b = dv >> 8;
        int r = atomicAdd(&cur[b], 1);
        ebuf[r] = (unsigned)sv | ((unsigned)(dv & 255) << 24);
    }
}

__global__ __launch_bounds__(256) void bucketfill_kernel(const unsigned int* __restrict__ ebuf,
                                                         const int* __restrict__ bucket_base,
                                                         int* __restrict__ row_start,
                                                         int* __restrict__ csr_src,
                                                         int n, int ne) {
    __shared__ unsigned int ed[P4CAP];
    __shared__ int deg_l[256];
    __shared__ int cur_l[256];
    __shared__ int wsum[4];
    int b = blockIdx.x, tid = threadIdx.x;
    int s = bucket_base[b];
    int cnt = bucket_base[b + 1] - s;
    deg_l[tid] = 0;
    __syncthreads();
    for (int t = tid; t < cnt; t += 256) {
        unsigned int e = ebuf[s + t];
        if (t < P4CAP) ed[t] = e;
        atomicAdd(&deg_l[e >> 24], 1);
    }
    __syncthreads();
    int v = deg_l[tid];
    int lane = tid & 63, w = tid >> 6;
    int incl = v;
#pragma unroll
    for (int off = 1; off < 64; off <<= 1) { int u = __shfl_up(incl, off); if (lane >= off) incl += u; }
    if (lane == 63) wsum[w] = incl;
    __syncthreads();
    int wofs = 0;
    for (int k = 0; k < w; ++k) wofs += wsum[k];
    int excl = wofs + incl - v;
    int node = b * 256 + tid;
    if (node < n) row_start[node] = s + excl;
    if (b == 0 && tid == 0) row_start[n] = ne;
    cur_l[tid] = excl;
    __syncthreads();
    for (int t = tid; t < cnt; t += 256) {
        unsigned int e = (t < P4CAP) ? ed[t] : ebuf[s + t];
        int d = e >> 24;
        int r = atomicAdd(&cur_l[d], 1);
        csr_src[s + r] = (int)(e & 0xFFFFFFu);
    }
}

// Wave-per-node CSR mean-gather from bf16 features, 16 neighbors in flight.
__global__ __launch_bounds__(256, 8) void gather_kernel(
    const unsigned short* __restrict__ xb, const int* __restrict__ row_start,
    const int* __restrict__ csr_src, unsigned short* __restrict__ aggb, int n) {
    int lane = threadIdx.x & 63;
    int i = (blockIdx.x * blockDim.x + threadIdx.x) >> 6;
    if (i >= n) return;
    int rs = row_start[i];
    int dg = row_start[i + 1] - rs;
    int g = lane >> 3, q = lane & 7;
    const unsigned short* xq = xb + q * 8;
    float av[8];
#pragma unroll
    for (int c = 0; c < 8; ++c) av[c] = 0.0f;

    for (int base = 0; base < dg; base += 64) {
        int cnt = min(dg - base, 64);
        int myidx = (lane < cnt) ? csr_src[rs + base + lane] : 0;
        for (int p = 0; p < cnt; p += 16) {
            int s0 = p + g, s1 = p + g + 8;
            int nb0 = __shfl(myidx, s0);
            int nb1 = __shfl(myidx, s1);
            bool a0 = s0 < cnt, a1 = s1 < cnt;
            uint4 v0, v1;
            if (a0) v0 = *reinterpret_cast<const uint4*>(xq + (size_t)nb0 * NFEAT);
            if (a1) v1 = *reinterpret_cast<const uint4*>(xq + (size_t)nb1 * NFEAT);
            if (a0) {
                av[0] += bf2f(v0.x & 0xffffu); av[1] += bf2f(v0.x >> 16);
                av[2] += bf2f(v0.y & 0xffffu); av[3] += bf2f(v0.y >> 16);
                av[4] += bf2f(v0.z & 0xffffu); av[5] += bf2f(v0.z >> 16);
                av[6] += bf2f(v0.w & 0xffffu); av[7] += bf2f(v0.w >> 16);
            }
            if (a1) {
                av[0] += bf2f(v1.x & 0xffffu); av[1] += bf2f(v1.x >> 16);
                av[2] += bf2f(v1.y & 0xffffu); av[3] += bf2f(v1.y >> 16);
                av[4] += bf2f(v1.z & 0xffffu); av[5] += bf2f(v1.z >> 16);
                av[6] += bf2f(v1.w & 0xffffu); av[7] += bf2f(v1.w >> 16);
            }
        }
    }
#pragma unroll
    for (int c = 0; c < 8; ++c) {
        av[c] += __shfl_xor(av[c], 8);
        av[c] += __shfl_xor(av[c], 16);
        av[c] += __shfl_xor(av[c], 32);
    }
    if (g == 0) {
        float r = 1.0f / (float)max(dg, 1);
        uint4 o;
        o.x = (unsigned)f2bf(av[0] * r) | ((unsigned)f2bf(av[1] * r) << 16);
        o.y = (unsigned)f2bf(av[2] * r) | ((unsigned)f2bf(av[3] * r) << 16);
        o.z = (unsigned)f2bf(av[4] * r) | ((unsigned)f2bf(av[5] * r) << 16);
        o.w = (unsigned)f2bf(av[6] * r) | ((unsigned)f2bf(av[7] * r) << 16);
        *reinterpret_cast<uint4*>(aggb + (size_t)i * NFEAT + q * 8) = o;
    }
}

// MFMA linear: h[n x 64] = [aggb | xb] @ wcat^T + bl. One wave = 16-node x 64-feat tile.
// BN stats: wave shfl-reduce -> LDS block reduce -> 2 atomic insts per block (64 lanes).
__global__ __launch_bounds__(256) void lin_mfma_kernel(
    const unsigned short* __restrict__ aggb, const unsigned short* __restrict__ xb,
    const unsigned short* __restrict__ wcat, const float* __restrict__ bl,
    float* __restrict__ h, float* __restrict__ stats, int n) {
    __shared__ float red1[4][64];
    __shared__ float red2[4][64];
    int lane = threadIdx.x & 63;
    int wave = threadIdx.x >> 6;
    int wid = (blockIdx.x * blockDim.x + threadIdx.x) >> 6;
    int nw = (gridDim.x * blockDim.x) >> 6;
    int r16 = lane & 15, kb = lane >> 4;

    bf16x8 bfrag[4][4];
#pragma unroll
    for (int kt = 0; kt < 4; ++kt)
#pragma unroll
        for (int nt = 0; nt < 4; ++nt)
            bfrag[kt][nt] = *reinterpret_cast<const bf16x8*>(
                wcat + (size_t)(nt * 16 + r16) * 128 + kt * 32 + kb * 8);

    float blj[4];
#pragma unroll
    for (int nt = 0; nt < 4; ++nt) blj[nt] = bl[nt * 16 + r16];

    float s1[4] = {0.f, 0.f, 0.f, 0.f}, s2[4] = {0.f, 0.f, 0.f, 0.f};
    int ntiles = (n + 15) >> 4;
    for (int t = wid; t < ntiles; t += nw) {
        int nbase = t << 4;
        int node = nbase + r16;
        size_t arow = (size_t)min(node, n - 1) * NFEAT;
        bf16x8 af[4];
        af[0] = *reinterpret_cast<const bf16x8*>(aggb + arow + kb * 8);
        af[1] = *reinterpret_cast<const bf16x8*>(aggb + arow + 32 + kb * 8);
        af[2] = *reinterpret_cast<const bf16x8*>(xb + arow + kb * 8);
        af[3] = *reinterpret_cast<const bf16x8*>(xb + arow + 32 + kb * 8);

        f32x4 acc[4] = {{0.f,0.f,0.f,0.f},{0.f,0.f,0.f,0.f},{0.f,0.f,0.f,0.f},{0.f,0.f,0.f,0.f}};
#pragma unroll
        for (int kt = 0; kt < 4; ++kt) {
#pragma unroll
            for (int nt = 0; nt < 4; ++nt)
                acc[nt] = __builtin_amdgcn_mfma_f32_16x16x32_bf16(af[kt], bfrag[kt][nt], acc[nt], 0, 0, 0);
        }
        if (nbase + 16 <= n) {
#pragma unroll
            for (int nt = 0; nt < 4; ++nt) {
#pragma unroll
                for (int reg = 0; reg < 4; ++reg) {
                    int ni = nbase + kb * 4 + reg;
                    float v = acc[nt][reg] + blj[nt];
                    h[(size_t)ni * NFEAT + nt * 16 + r16] = v;
                    s1[nt] += v;
                    s2[nt] += v * v;
                }
            }
        } else {
#pragma unroll
            for (int nt = 0; nt < 4; ++nt) {
#pragma unroll
                for (int reg = 0; reg < 4; ++reg) {
                    int ni = nbase + kb * 4 + reg;
                    if (ni < n) {
                        float v = acc[nt][reg] + blj[nt];
                        h[(size_t)ni * NFEAT + nt * 16 + r16] = v;
                        s1[nt] += v;
                        s2[nt] += v * v;
                    }
                }
            }
        }
    }
#pragma unroll
    for (int nt = 0; nt < 4; ++nt) {
        s1[nt] += __shfl_xor(s1[nt], 16); s1[nt] += __shfl_xor(s1[nt], 32);
        s2[nt] += __shfl_xor(s2[nt], 16); s2[nt] += __shfl_xor(s2[nt], 32);
    }
    if (lane < 16) {
#pragma unroll
        for (int nt = 0; nt < 4; ++nt) {
            red1[wave][nt * 16 + lane] = s1[nt];
            red2[wave][nt * 16 + lane] = s2[nt];
        }
    }
    __syncthreads();
    if (wave == 0) {
        float t1 = red1[0][lane] + red1[1][lane] + red1[2][lane] + red1[3][lane];
        float t2 = red2[0][lane] + red2[1][lane] + red2[2][lane] + red2[3][lane];
        atomicAdd(&stats[lane], t1);
        atomicAdd(&stats[64 + lane], t2);
    }
}

// BN (training stats) + ReLU; emits bf16 next-layer features (if hbf) and pool
// accumulation via LDS (batch sorted).
__global__ __launch_bounds__(256) void bn_kernel(
    const float* __restrict__ h, unsigned short* __restrict__ hbf,
    const float* __restrict__ stats,
    const float* __restrict__ g, const float* __restrict__ b,
    const int* __restrict__ batch, float* __restrict__ pool,
    int colbase, int n) {
    __shared__ float pl[BN_SPAN][64];
    __shared__ int gmin_s, span_s;
    int tid = threadIdx.x;
    int j = tid & 63;
    int sub = tid >> 6;
    int nbase = blockIdx.x * BN_NODES;
    if (nbase >= n) return;

    if (tid == 0) {
        int last = min(nbase + BN_NODES, n) - 1;
        gmin_s = batch[nbase];
        span_s = batch[last] - gmin_s + 1;
    }
    __syncthreads();
    int gmin = gmin_s, span = span_s;
    bool use_lds = (span <= BN_SPAN);
    if (use_lds) {
        for (int t = tid; t < span * 64; t += 256) ((float*)pl)[t] = 0.0f;
    }
    __syncthreads();

    float invn = 1.0f / (float)n;
    float mu = stats[j] * invn;
    float var = stats[64 + j] * invn - mu * mu;
    float sc = rsqrtf(var + 1e-5f) * g[j];
    float bb = b[j];

    for (int r = sub; r < BN_NODES; r += 4) {
        int i = nbase + r;
        if (i >= n) break;
        size_t idx = (size_t)i * NFEAT + j;
        float v = fmaxf((h[idx] - mu) * sc + bb, 0.0f);
        if (hbf) hbf[idx] = f2bf(v);
        int gi = batch[i];
        if (use_lds) atomicAdd(&pl[gi - gmin][j], v);
        else atomicAdd(&pool[(size_t)gi * NCAT + colbase + j], v);
    }
    __syncthreads();
    if (use_lds) {
        for (int t = tid; t < span * 64; t += 256) {
            int s = t >> 6, j2 = t & 63;
            float v = pl[s][j2];
            if (v != 0.0f) atomicAdd(&pool[(size_t)(gmin + s) * NCAT + colbase + j2], v);
        }
    }
}

__global__ void final_kernel(const float* __restrict__ pool, const float* __restrict__ cnt,
                             float* __restrict__ out, int total) {
    int t = blockIdx.x * blockDim.x + threadIdx.x;
    if (t >= total) return;
    int gidx = t / NCAT;
    out[t] = pool[t] / fmaxf(cnt[gidx], 1.0f);
}

extern "C" void kernel_launch(void* const* d_in, const int* in_sizes, int n_in,
                              void* d_out, int out_size, void* d_ws, size_t ws_size,
                              hipStream_t stream) {
    const float* x = (const float*)d_in[0];
    const int* ei = (const int*)d_in[1];
    const int* batch = (const int*)d_in[2];

    const float* Wl[3], *bl[3], *Wr[3], *gm[3], *bt[3];
    for (int L = 0; L < 3; ++L) {
        Wl[L] = (const float*)d_in[3 + 5 * L + 0];
        bl[L] = (const float*)d_in[3 + 5 * L + 1];
        Wr[L] = (const float*)d_in[3 + 5 * L + 2];
        gm[L] = (const float*)d_in[3 + 5 * L + 3];
        bt[L] = (const float*)d_in[3 + 5 * L + 4];
    }

    const int n = in_sizes[0] / NFEAT;
    const int ne = in_sizes[1] / 2;
    const int ngraphs = out_size / NCAT;
    const int nbuck = (n + 255) >> 8;
    const int* src = ei;
    const int* dstp = ei + ne;

    char* wsb = (char*)d_ws;
    size_t off = 0;
    float* h = (float*)(wsb + off);      off += (size_t)n * NFEAT * 4;
    unsigned short* aggb = (unsigned short*)(wsb + off); off += (size_t)n * NFEAT * 2;
    unsigned short* xbA = (unsigned short*)(wsb + off);  off += (size_t)n * NFEAT * 2;
    unsigned short* xbB = (unsigned short*)(wsb + off);  off += (size_t)n * NFEAT * 2;
    unsigned short* wcat = (unsigned short*)(wsb + off); off += 3 * 64 * 128 * 2;
    int* csr_src = (int*)(wsb + off);    off += (size_t)ne * 4;
    unsigned int* ebuf = (unsigned int*)(wsb + off); off += (size_t)ne * 4;
    int* row_start = (int*)(wsb + off);  off += (size_t)(n + 1) * 4;
    int* C = (int*)(wsb + off);          off += (size_t)nbuck * NBLK * 4;
    int* Cs = (int*)(wsb + off);         off += (size_t)nbuck * NBLK * 4;
    int* coltot = (int*)(wsb + off);     off += (size_t)nbuck * 4;
    int* bucket_base = (int*)(wsb + off); off += (size_t)(nbuck + 1) * 4;
    float* stats = (float*)(wsb + off);  off += 128 * 4;
    float* pool = (float*)(wsb + off);   off += (size_t)ngraphs * NCAT * 4;
    float* cntf = (float*)(wsb + off);   off += (size_t)ngraphs * 4;

    hipMemsetAsync(cntf, 0, (size_t)ngraphs * sizeof(float), stream);
    hipMemsetAsync(pool, 0, (size_t)ngraphs * NCAT * sizeof(float), stream);

    hist_kernel<<<NBLK, 256, 0, stream>>>(dstp, C, ne, nbuck);
    colscan_kernel<<<nbuck, NBLK, 0, stream>>>(C, Cs, coltot);
    topscan_kernel<<<1, 1024, 0, stream>>>(coltot, bucket_base, nbuck, ne);
    scatter3_kernel<<<NBLK, 256, 0, stream>>>(src, dstp, Cs, bucket_base, ebuf, ne, nbuck);
    bucketfill_kernel<<<nbuck, 256, 0, stream>>>(ebuf, bucket_base, row_start, csr_src, n, ne);

    cnt_kernel<<<(n + 255) / 256, 256, 0, stream>>>(batch, cntf, n);
    cvt_kernel<<<((n * NFEAT / 4) + 255) / 256, 256, 0, stream>>>(x, xbA, n * NFEAT / 4);
    wprep_kernel<<<(3 * 64 * 128 + 255) / 256, 256, 0, stream>>>(
        Wl[0], Wr[0], Wl[1], Wr[1], Wl[2], Wr[2], wcat);

    const unsigned short* gin[3] = {xbA, xbB, xbA};
    unsigned short* gout[3] = {xbB, xbA, nullptr};
    for (int L = 0; L < 3; ++L) {
        hipMemsetAsync(stats, 0, 128 * sizeof(float), stream);
        gather_kernel<<<(n + 3) / 4, 256, 0, stream>>>(gin[L], row_start, csr_src, aggb, n);
        lin_mfma_kernel<<<256, 256, 0, stream>>>(aggb, gin[L], wcat + (size_t)L * 8192,
                                                 bl[L], h, stats, n);
        bn_kernel<<<(n + BN_NODES - 1) / BN_NODES, 256, 0, stream>>>(
            h, gout[L], stats, gm[L], bt[L], batch, pool, L * NFEAT, n);
    }
    final_kernel<<<(out_size + 255) / 256, 256, 0, stream>>>(pool, cntf, (float*)d_out, out_size);
}

// Round 7
// 371.047 us; speedup vs baseline: 5.6764x; 1.2587x over previous
//
#include <hip/hip_runtime.h>

#define NFEAT 64
#define NCAT 192
#define BN_NODES 32
#define BN_SPAN 8
#define NBLK 128
#define P4CAP 4608

typedef float f32x4 __attribute__((ext_vector_type(4)));
typedef short bf16x8 __attribute__((ext_vector_type(8)));

__device__ __forceinline__ float bf2f(unsigned int u16) {
    union { unsigned int i; float f; } c; c.i = u16 << 16; return c.f;
}
__device__ __forceinline__ unsigned short f2bf(float f) {
    union { float f; unsigned int i; } c; c.f = f;
    unsigned int r = c.i + 0x7fffu + ((c.i >> 16) & 1u);
    return (unsigned short)(r >> 16);
}

// Per-graph node counts via binary search on the sorted batch array (no atomics).
__global__ void cntb_kernel(const int* __restrict__ batch, float* __restrict__ cnt,
                            int n, int ngraphs) {
    int g = blockIdx.x * blockDim.x + threadIdx.x;
    if (g >= ngraphs) return;
    int lo = 0, hi = n;
    while (lo < hi) { int mid = (lo + hi) >> 1; if (batch[mid] < g) lo = mid + 1; else hi = mid; }
    int a = lo;
    lo = 0; hi = n;
    int g1 = g + 1;
    while (lo < hi) { int mid = (lo + hi) >> 1; if (batch[mid] < g1) lo = mid + 1; else hi = mid; }
    cnt[g] = (float)(lo - a);
}

__global__ void cvt_kernel(const float* __restrict__ x, unsigned short* __restrict__ xb, int total4) {
    int t = blockIdx.x * blockDim.x + threadIdx.x;
    if (t < total4) {
        float4 v = reinterpret_cast<const float4*>(x)[t];
        ushort4 o;
        o.x = f2bf(v.x); o.y = f2bf(v.y); o.z = f2bf(v.z); o.w = f2bf(v.w);
        reinterpret_cast<ushort4*>(xb)[t] = o;
    }
}

__global__ void wprep_kernel(const float* __restrict__ Wl0, const float* __restrict__ Wr0,
                             const float* __restrict__ Wl1, const float* __restrict__ Wr1,
                             const float* __restrict__ Wl2, const float* __restrict__ Wr2,
                             unsigned short* __restrict__ wcat) {
    int t = blockIdx.x * blockDim.x + threadIdx.x;
    if (t >= 3 * 64 * 128) return;
    int L = t >> 13;
    int r = t & 8191;
    int f = r >> 7, k = r & 127;
    const float* Wl = (L == 0) ? Wl0 : (L == 1) ? Wl1 : Wl2;
    const float* Wr = (L == 0) ? Wr0 : (L == 1) ? Wr1 : Wr2;
    float v = (k < 64) ? Wl[f * 64 + k] : Wr[f * 64 + (k - 64)];
    wcat[t] = f2bf(v);
}

// ---- CSR build as two-level counting sort (bucket = dst >> 8) ----

__global__ __launch_bounds__(256) void hist_kernel(const int* __restrict__ dst,
                                                   int* __restrict__ C, int ne, int nbuck) {
    __shared__ int hist[1024];
    int blk = blockIdx.x, tid = threadIdx.x;
    for (int t = tid; t < nbuck; t += 256) hist[t] = 0;
    __syncthreads();
    int chunk = (ne + NBLK - 1) / NBLK;
    int s = blk * chunk, e_end = min(s + chunk, ne);
    for (int e = s + tid; e < e_end; e += 256) atomicAdd(&hist[dst[e] >> 8], 1);
    __syncthreads();
    for (int t = tid; t < nbuck; t += 256) C[t * NBLK + blk] = hist[t];
}

__global__ __launch_bounds__(128) void colscan_kernel(const int* __restrict__ C,
                                                      int* __restrict__ Cs,
                                                      int* __restrict__ coltot) {
    __shared__ int wt[2];
    int b = blockIdx.x, t = threadIdx.x;
    int v = C[b * NBLK + t];
    int lane = t & 63, w = t >> 6;
    int incl = v;
#pragma unroll
    for (int off = 1; off < 64; off <<= 1) { int u = __shfl_up(incl, off); if (lane >= off) incl += u; }
    if (lane == 63) wt[w] = incl;
    __syncthreads();
    int excl = incl - v + ((w == 1) ? wt[0] : 0);
    Cs[b * NBLK + t] = excl;
    if (t == NBLK - 1) coltot[b] = excl + v;
}

__global__ __launch_bounds__(1024) void topscan_kernel(const int* __restrict__ coltot,
                                                       int* __restrict__ bucket_base,
                                                       int nbuck, int ne) {
    __shared__ int a[1024];
    int t = threadIdx.x;
    int v = (t < nbuck) ? coltot[t] : 0;
    a[t] = v;
    __syncthreads();
    for (int off = 1; off < 1024; off <<= 1) {
        int u = (t >= off) ? a[t - off] : 0;
        __syncthreads();
        a[t] += u;
        __syncthreads();
    }
    if (t < nbuck) bucket_base[t] = a[t] - v;
    if (t == 0) bucket_base[nbuck] = ne;
}

__global__ __launch_bounds__(256) void scatter3_kernel(const int* __restrict__ src,
                                                       const int* __restrict__ dst,
                                                       const int* __restrict__ Cs,
                                                       const int* __restrict__ bucket_base,
                                                       unsigned int* __restrict__ ebuf,
                                                       int ne, int nbuck) {
    __shared__ int cur[1024];
    int blk = blockIdx.x, tid = threadIdx.x;
    for (int t = tid; t < nbuck; t += 256) cur[t] = bucket_base[t] + Cs[t * NBLK + blk];
    __syncthreads();
    int chunk = (ne + NBLK - 1) / NBLK;
    int s = blk * chunk, e_end = min(s + chunk, ne);
    for (int e = s + tid; e < e_end; e += 256) {
        int sv = src[e], dv = dst[e];
        int b = dv >> 8;
        int r = atomicAdd(&cur[b], 1);
        ebuf[r] = (unsigned)sv | ((unsigned)(dv & 255) << 24);
    }
}

__global__ __launch_bounds__(256) void bucketfill_kernel(const unsigned int* __restrict__ ebuf,
                                                         const int* __restrict__ bucket_base,
                                                         int* __restrict__ row_start,
                                                         int* __restrict__ csr_src,
                                                         int n, int ne) {
    __shared__ unsigned int ed[P4CAP];
    __shared__ int deg_l[256];
    __shared__ int cur_l[256];
    __shared__ int wsum[4];
    int b = blockIdx.x, tid = threadIdx.x;
    int s = bucket_base[b];
    int cnt = bucket_base[b + 1] - s;
    deg_l[tid] = 0;
    __syncthreads();
    for (int t = tid; t < cnt; t += 256) {
        unsigned int e = ebuf[s + t];
        if (t < P4CAP) ed[t] = e;
        atomicAdd(&deg_l[e >> 24], 1);
    }
    __syncthreads();
    int v = deg_l[tid];
    int lane = tid & 63, w = tid >> 6;
    int incl = v;
#pragma unroll
    for (int off = 1; off < 64; off <<= 1) { int u = __shfl_up(incl, off); if (lane >= off) incl += u; }
    if (lane == 63) wsum[w] = incl;
    __syncthreads();
    int wofs = 0;
    for (int k = 0; k < w; ++k) wofs += wsum[k];
    int excl = wofs + incl - v;
    int node = b * 256 + tid;
    if (node < n) row_start[node] = s + excl;
    if (b == 0 && tid == 0) row_start[n] = ne;
    cur_l[tid] = excl;
    __syncthreads();
    for (int t = tid; t < cnt; t += 256) {
        unsigned int e = (t < P4CAP) ? ed[t] : ebuf[s + t];
        int d = e >> 24;
        int r = atomicAdd(&cur_l[d], 1);
        csr_src[s + r] = (int)(e & 0xFFFFFFu);
    }
}

// Wave-per-node CSR mean-gather from bf16 features, up to 32 neighbors in flight
// (4 guarded 16B loads issued per lane before consumption).
__global__ __launch_bounds__(256, 8) void gather_kernel(
    const unsigned short* __restrict__ xb, const int* __restrict__ row_start,
    const int* __restrict__ csr_src, unsigned short* __restrict__ aggb, int n) {
    int lane = threadIdx.x & 63;
    int i = (blockIdx.x * blockDim.x + threadIdx.x) >> 6;
    if (i >= n) return;
    int rs = row_start[i];
    int dg = row_start[i + 1] - rs;
    int g = lane >> 3, q = lane & 7;
    const unsigned short* xq = xb + q * 8;
    float av[8];
#pragma unroll
    for (int c = 0; c < 8; ++c) av[c] = 0.0f;

    for (int base = 0; base < dg; base += 64) {
        int cnt = min(dg - base, 64);
        int myidx = (lane < cnt) ? csr_src[rs + base + lane] : 0;
        for (int p = 0; p < cnt; p += 32) {
            int s0 = p + g, s1 = s0 + 8, s2 = s0 + 16, s3 = s0 + 24;
            int nb0 = __shfl(myidx, s0);
            int nb1 = __shfl(myidx, s1);
            int nb2 = __shfl(myidx, s2);
            int nb3 = __shfl(myidx, s3);
            bool a0 = s0 < cnt, a1 = s1 < cnt, a2 = s2 < cnt, a3 = s3 < cnt;
            uint4 v0, v1, v2, v3;
            if (a0) v0 = *reinterpret_cast<const uint4*>(xq + (size_t)nb0 * NFEAT);
            if (a1) v1 = *reinterpret_cast<const uint4*>(xq + (size_t)nb1 * NFEAT);
            if (a2) v2 = *reinterpret_cast<const uint4*>(xq + (size_t)nb2 * NFEAT);
            if (a3) v3 = *reinterpret_cast<const uint4*>(xq + (size_t)nb3 * NFEAT);
            if (a0) {
                av[0] += bf2f(v0.x & 0xffffu); av[1] += bf2f(v0.x >> 16);
                av[2] += bf2f(v0.y & 0xffffu); av[3] += bf2f(v0.y >> 16);
                av[4] += bf2f(v0.z & 0xffffu); av[5] += bf2f(v0.z >> 16);
                av[6] += bf2f(v0.w & 0xffffu); av[7] += bf2f(v0.w >> 16);
            }
            if (a1) {
                av[0] += bf2f(v1.x & 0xffffu); av[1] += bf2f(v1.x >> 16);
                av[2] += bf2f(v1.y & 0xffffu); av[3] += bf2f(v1.y >> 16);
                av[4] += bf2f(v1.z & 0xffffu); av[5] += bf2f(v1.z >> 16);
                av[6] += bf2f(v1.w & 0xffffu); av[7] += bf2f(v1.w >> 16);
            }
            if (a2) {
                av[0] += bf2f(v2.x & 0xffffu); av[1] += bf2f(v2.x >> 16);
                av[2] += bf2f(v2.y & 0xffffu); av[3] += bf2f(v2.y >> 16);
                av[4] += bf2f(v2.z & 0xffffu); av[5] += bf2f(v2.z >> 16);
                av[6] += bf2f(v2.w & 0xffffu); av[7] += bf2f(v2.w >> 16);
            }
            if (a3) {
                av[0] += bf2f(v3.x & 0xffffu); av[1] += bf2f(v3.x >> 16);
                av[2] += bf2f(v3.y & 0xffffu); av[3] += bf2f(v3.y >> 16);
                av[4] += bf2f(v3.z & 0xffffu); av[5] += bf2f(v3.z >> 16);
                av[6] += bf2f(v3.w & 0xffffu); av[7] += bf2f(v3.w >> 16);
            }
        }
    }
#pragma unroll
    for (int c = 0; c < 8; ++c) {
        av[c] += __shfl_xor(av[c], 8);
        av[c] += __shfl_xor(av[c], 16);
        av[c] += __shfl_xor(av[c], 32);
    }
    if (g == 0) {
        float r = 1.0f / (float)max(dg, 1);
        uint4 o;
        o.x = (unsigned)f2bf(av[0] * r) | ((unsigned)f2bf(av[1] * r) << 16);
        o.y = (unsigned)f2bf(av[2] * r) | ((unsigned)f2bf(av[3] * r) << 16);
        o.z = (unsigned)f2bf(av[4] * r) | ((unsigned)f2bf(av[5] * r) << 16);
        o.w = (unsigned)f2bf(av[6] * r) | ((unsigned)f2bf(av[7] * r) << 16);
        *reinterpret_cast<uint4*>(aggb + (size_t)i * NFEAT + q * 8) = o;
    }
}

// MFMA linear: h[n x 64] = [aggb | xb] @ wcat^T + bl. One wave = 16-node x 64-feat tile.
// BN stats: wave shfl-reduce -> LDS block reduce -> 2 atomic insts per block.
__global__ __launch_bounds__(256) void lin_mfma_kernel(
    const unsigned short* __restrict__ aggb, const unsigned short* __restrict__ xb,
    const unsigned short* __restrict__ wcat, const float* __restrict__ bl,
    float* __restrict__ h, float* __restrict__ stats, int n) {
    __shared__ float red1[4][64];
    __shared__ float red2[4][64];
    int lane = threadIdx.x & 63;
    int wave = threadIdx.x >> 6;
    int wid = (blockIdx.x * blockDim.x + threadIdx.x) >> 6;
    int nw = (gridDim.x * blockDim.x) >> 6;
    int r16 = lane & 15, kb = lane >> 4;

    bf16x8 bfrag[4][4];
#pragma unroll
    for (int kt = 0; kt < 4; ++kt)
#pragma unroll
        for (int nt = 0; nt < 4; ++nt)
            bfrag[kt][nt] = *reinterpret_cast<const bf16x8*>(
                wcat + (size_t)(nt * 16 + r16) * 128 + kt * 32 + kb * 8);

    float blj[4];
#pragma unroll
    for (int nt = 0; nt < 4; ++nt) blj[nt] = bl[nt * 16 + r16];

    float s1[4] = {0.f, 0.f, 0.f, 0.f}, s2[4] = {0.f, 0.f, 0.f, 0.f};
    int ntiles = (n + 15) >> 4;
    for (int t = wid; t < ntiles; t += nw) {
        int nbase = t << 4;
        int node = nbase + r16;
        size_t arow = (size_t)min(node, n - 1) * NFEAT;
        bf16x8 af[4];
        af[0] = *reinterpret_cast<const bf16x8*>(aggb + arow + kb * 8);
        af[1] = *reinterpret_cast<const bf16x8*>(aggb + arow + 32 + kb * 8);
        af[2] = *reinterpret_cast<const bf16x8*>(xb + arow + kb * 8);
        af[3] = *reinterpret_cast<const bf16x8*>(xb + arow + 32 + kb * 8);

        f32x4 acc[4] = {{0.f,0.f,0.f,0.f},{0.f,0.f,0.f,0.f},{0.f,0.f,0.f,0.f},{0.f,0.f,0.f,0.f}};
#pragma unroll
        for (int kt = 0; kt < 4; ++kt) {
#pragma unroll
            for (int nt = 0; nt < 4; ++nt)
                acc[nt] = __builtin_amdgcn_mfma_f32_16x16x32_bf16(af[kt], bfrag[kt][nt], acc[nt], 0, 0, 0);
        }
        if (nbase + 16 <= n) {
#pragma unroll
            for (int nt = 0; nt < 4; ++nt) {
#pragma unroll
                for (int reg = 0; reg < 4; ++reg) {
                    int ni = nbase + kb * 4 + reg;
                    float v = acc[nt][reg] + blj[nt];
                    h[(size_t)ni * NFEAT + nt * 16 + r16] = v;
                    s1[nt] += v;
                    s2[nt] += v * v;
                }
            }
        } else {
#pragma unroll
            for (int nt = 0; nt < 4; ++nt) {
#pragma unroll
                for (int reg = 0; reg < 4; ++reg) {
                    int ni = nbase + kb * 4 + reg;
                    if (ni < n) {
                        float v = acc[nt][reg] + blj[nt];
                        h[(size_t)ni * NFEAT + nt * 16 + r16] = v;
                        s1[nt] += v;
                        s2[nt] += v * v;
                    }
                }
            }
        }
    }
#pragma unroll
    for (int nt = 0; nt < 4; ++nt) {
        s1[nt] += __shfl_xor(s1[nt], 16); s1[nt] += __shfl_xor(s1[nt], 32);
        s2[nt] += __shfl_xor(s2[nt], 16); s2[nt] += __shfl_xor(s2[nt], 32);
    }
    if (lane < 16) {
#pragma unroll
        for (int nt = 0; nt < 4; ++nt) {
            red1[wave][nt * 16 + lane] = s1[nt];
            red2[wave][nt * 16 + lane] = s2[nt];
        }
    }
    __syncthreads();
    if (wave == 0) {
        float t1 = red1[0][lane] + red1[1][lane] + red1[2][lane] + red1[3][lane];
        float t2 = red2[0][lane] + red2[1][lane] + red2[2][lane] + red2[3][lane];
        atomicAdd(&stats[lane], t1);
        atomicAdd(&stats[64 + lane], t2);
    }
}

// BN (training stats) + ReLU; emits bf16 next-layer features (if hbf) and pool
// accumulation via LDS (batch sorted).
__global__ __launch_bounds__(256) void bn_kernel(
    const float* __restrict__ h, unsigned short* __restrict__ hbf,
    const float* __restrict__ stats,
    const float* __restrict__ g, const float* __restrict__ b,
    const int* __restrict__ batch, float* __restrict__ pool,
    int colbase, int n) {
    __shared__ float pl[BN_SPAN][64];
    __shared__ int gmin_s, span_s;
    int tid = threadIdx.x;
    int j = tid & 63;
    int sub = tid >> 6;
    int nbase = blockIdx.x * BN_NODES;
    if (nbase >= n) return;

    if (tid == 0) {
        int last = min(nbase + BN_NODES, n) - 1;
        gmin_s = batch[nbase];
        span_s = batch[last] - gmin_s + 1;
    }
    __syncthreads();
    int gmin = gmin_s, span = span_s;
    bool use_lds = (span <= BN_SPAN);
    if (use_lds) {
        for (int t = tid; t < span * 64; t += 256) ((float*)pl)[t] = 0.0f;
    }
    __syncthreads();

    float invn = 1.0f / (float)n;
    float mu = stats[j] * invn;
    float var = stats[64 + j] * invn - mu * mu;
    float sc = rsqrtf(var + 1e-5f) * g[j];
    float bb = b[j];

    for (int r = sub; r < BN_NODES; r += 4) {
        int i = nbase + r;
        if (i >= n) break;
        size_t idx = (size_t)i * NFEAT + j;
        float v = fmaxf((h[idx] - mu) * sc + bb, 0.0f);
        if (hbf) hbf[idx] = f2bf(v);
        int gi = batch[i];
        if (use_lds) atomicAdd(&pl[gi - gmin][j], v);
        else atomicAdd(&pool[(size_t)gi * NCAT + colbase + j], v);
    }
    __syncthreads();
    if (use_lds) {
        for (int t = tid; t < span * 64; t += 256) {
            int s = t >> 6, j2 = t & 63;
            float v = pl[s][j2];
            if (v != 0.0f) atomicAdd(&pool[(size_t)(gmin + s) * NCAT + colbase + j2], v);
        }
    }
}

__global__ void final_kernel(const float* __restrict__ pool, const float* __restrict__ cnt,
                             float* __restrict__ out, int total) {
    int t = blockIdx.x * blockDim.x + threadIdx.x;
    if (t >= total) return;
    int gidx = t / NCAT;
    out[t] = pool[t] / fmaxf(cnt[gidx], 1.0f);
}

extern "C" void kernel_launch(void* const* d_in, const int* in_sizes, int n_in,
                              void* d_out, int out_size, void* d_ws, size_t ws_size,
                              hipStream_t stream) {
    const float* x = (const float*)d_in[0];
    const int* ei = (const int*)d_in[1];
    const int* batch = (const int*)d_in[2];

    const float* Wl[3], *bl[3], *Wr[3], *gm[3], *bt[3];
    for (int L = 0; L < 3; ++L) {
        Wl[L] = (const float*)d_in[3 + 5 * L + 0];
        bl[L] = (const float*)d_in[3 + 5 * L + 1];
        Wr[L] = (const float*)d_in[3 + 5 * L + 2];
        gm[L] = (const float*)d_in[3 + 5 * L + 3];
        bt[L] = (const float*)d_in[3 + 5 * L + 4];
    }

    const int n = in_sizes[0] / NFEAT;
    const int ne = in_sizes[1] / 2;
    const int ngraphs = out_size / NCAT;
    const int nbuck = (n + 255) >> 8;
    const int* src = ei;
    const int* dstp = ei + ne;

    char* wsb = (char*)d_ws;
    size_t off = 0;
    float* h = (float*)(wsb + off);      off += (size_t)n * NFEAT * 4;
    unsigned short* aggb = (unsigned short*)(wsb + off); off += (size_t)n * NFEAT * 2;
    unsigned short* xbA = (unsigned short*)(wsb + off);  off += (size_t)n * NFEAT * 2;
    unsigned short* xbB = (unsigned short*)(wsb + off);  off += (size_t)n * NFEAT * 2;
    unsigned short* wcat = (unsigned short*)(wsb + off); off += 3 * 64 * 128 * 2;
    int* csr_src = (int*)(wsb + off);    off += (size_t)ne * 4;
    unsigned int* ebuf = (unsigned int*)(wsb + off); off += (size_t)ne * 4;
    int* row_start = (int*)(wsb + off);  off += (size_t)(n + 1) * 4;
    int* C = (int*)(wsb + off);          off += (size_t)nbuck * NBLK * 4;
    int* Cs = (int*)(wsb + off);         off += (size_t)nbuck * NBLK * 4;
    int* coltot = (int*)(wsb + off);     off += (size_t)nbuck * 4;
    int* bucket_base = (int*)(wsb + off); off += (size_t)(nbuck + 1) * 4;
    float* stats = (float*)(wsb + off);  off += 128 * 4;
    float* pool = (float*)(wsb + off);   off += (size_t)ngraphs * NCAT * 4;
    float* cntf = (float*)(wsb + off);   off += (size_t)ngraphs * 4;

    hipMemsetAsync(pool, 0, (size_t)ngraphs * NCAT * sizeof(float), stream);

    hist_kernel<<<NBLK, 256, 0, stream>>>(dstp, C, ne, nbuck);
    colscan_kernel<<<nbuck, NBLK, 0, stream>>>(C, Cs, coltot);
    topscan_kernel<<<1, 1024, 0, stream>>>(coltot, bucket_base, nbuck, ne);
    scatter3_kernel<<<NBLK, 256, 0, stream>>>(src, dstp, Cs, bucket_base, ebuf, ne, nbuck);
    bucketfill_kernel<<<nbuck, 256, 0, stream>>>(ebuf, bucket_base, row_start, csr_src, n, ne);

    cntb_kernel<<<(ngraphs + 255) / 256, 256, 0, stream>>>(batch, cntf, n, ngraphs);
    cvt_kernel<<<((n * NFEAT / 4) + 255) / 256, 256, 0, stream>>>(x, xbA, n * NFEAT / 4);
    wprep_kernel<<<(3 * 64 * 128 + 255) / 256, 256, 0, stream>>>(
        Wl[0], Wr[0], Wl[1], Wr[1], Wl[2], Wr[2], wcat);

    const unsigned short* gin[3] = {xbA, xbB, xbA};
    unsigned short* gout[3] = {xbB, xbA, nullptr};
    for (int L = 0; L < 3; ++L) {
        hipMemsetAsync(stats, 0, 128 * sizeof(float), stream);
        gather_kernel<<<(n + 3) / 4, 256, 0, stream>>>(gin[L], row_start, csr_src, aggb, n);
        lin_mfma_kernel<<<256, 256, 0, stream>>>(aggb, gin[L], wcat + (size_t)L * 8192,
                                                 bl[L], h, stats, n);
        bn_kernel<<<(n + BN_NODES - 1) / BN_NODES, 256, 0, stream>>>(
            h, gout[L], stats, gm[L], bt[L], batch, pool, L * NFEAT, n);
    }
    final_kernel<<<(out_size + 255) / 256, 256, 0, stream>>>(pool, cntf, (float*)d_out, out_size);
}